// Round 9
// baseline (499.372 us; speedup 1.0000x reference)
//
#include <hip/hip_runtime.h>
#include <hip/hip_bf16.h>
#include <cstddef>

// ---------------------------------------------------------------------------
// LSTMSeq2Seq: B=4096, L=64, T=48, H=64, NH=4, HD=16, NQ=3
// Round 9: anti-phased layer-split LSTM — every phase runs one layer's GEMM
// (MFMA pipe, 8 waves) concurrently with the other layer's cell (VALU pipe,
// 8 waves). A2 double-buffered by step parity. Attn chain unchanged.
// ---------------------------------------------------------------------------

#define B_   4096
#define L_   64
#define T_   48
#define H_   64
#define ROWS 16      // batch rows per LSTM block
#define PADH 136     // LSTM A row pad (halves)
#define GBS  260     // gb row stride (floats)

using half8  = __attribute__((ext_vector_type(8))) _Float16;
using half4  = __attribute__((ext_vector_type(4))) _Float16;
using f32x4  = __attribute__((ext_vector_type(4))) float;

#define IC_ 4.8828125e-4f   // 2^-11

// native-rate transcendentals (v_exp_f32 + v_rcp_f32); overflow-safe forms
__device__ __forceinline__ float fsig(float x) {
    return __builtin_amdgcn_rcpf(1.0f + __expf(-x));
}
__device__ __forceinline__ float ftanh(float x) {
    float e = __expf(-2.0f * fabsf(x));            // e in (0,1], never overflows
    float r = (1.0f - e) * __builtin_amdgcn_rcpf(1.0f + e);
    return copysignf(r, x);
}

// ---------------------------------------------------------------------------
// LSTM weight split (one-time): whalf[split][gate_row 256][k 128]
// ---------------------------------------------------------------------------
__global__ void transpose_w_kernel(const float* __restrict__ Wih,
                                   const float* __restrict__ Whh,
                                   _Float16* __restrict__ out) {
    int idx = blockIdx.x * 256 + threadIdx.x;
    if (idx >= 16384) return;
    int r = idx >> 6, k = idx & 63;
    float wi = Wih[idx];
    _Float16 hi = (_Float16)wi;
    out[r * 128 + k] = hi;
    out[32768 + r * 128 + k] = (_Float16)((wi - (float)hi) * 2048.0f);
    float wh = Whh[idx];
    hi = (_Float16)wh;
    out[r * 128 + 64 + k] = hi;
    out[32768 + r * 128 + 64 + k] = (_Float16)((wh - (float)hi) * 2048.0f);
}

// Attention weight splits: wqkvh[2][192][64], woh[2][64][64], w1h[2][32][64]
__global__ void split_aux_kernel(const float* __restrict__ Wqkv,
                                 const float* __restrict__ Wo,
                                 const float* __restrict__ W1,
                                 _Float16* __restrict__ wqkvh,
                                 _Float16* __restrict__ woh,
                                 _Float16* __restrict__ w1h) {
    int idx = blockIdx.x * 256 + threadIdx.x;
    if (idx < 12288) {
        float v = Wqkv[idx]; _Float16 h = (_Float16)v;
        wqkvh[idx] = h; wqkvh[12288 + idx] = (_Float16)((v - (float)h) * 2048.f);
    } else if (idx < 16384) {
        int i = idx - 12288;
        float v = Wo[i]; _Float16 h = (_Float16)v;
        woh[i] = h; woh[4096 + i] = (_Float16)((v - (float)h) * 2048.f);
    } else if (idx < 18432) {
        int i = idx - 16384;
        float v = W1[i]; _Float16 h = (_Float16)v;
        w1h[i] = h; w1h[2048 + i] = (_Float16)((v - (float)h) * 2048.f);
    }
}

// ---------------------------------------------------------------------------
// Fused 2-layer LSTM, anti-phased. 256 blocks x 1024 threads (16 waves).
// Waves 0-7: layer-1 (GEMM in phase A, cell in phase B).
// Waves 8-15: layer-2 (cell in phase A, GEMM in phase B).
// Schedule: P_A(i) = {L1G(i), L2C(i-2)};  P_B(i) = {L1C(i), L2G(i-1)}.
// A2 double-buffered by step parity:
//   L1C(i) -> A2buf[i&1] x-part;  L2C(j) -> A2buf[(j+1)&1] h-part;
//   L2G(j2) reads A2buf[j2&1].
// ---------------------------------------------------------------------------
__global__ __launch_bounds__(1024, 4) void lstm2_mfma_kernel(
    const float* __restrict__ inseq,
    const float* __restrict__ in0,
    const _Float16* __restrict__ w1half,
    const float* __restrict__ b1ihp, const float* __restrict__ b1hhp,
    const _Float16* __restrict__ w2half,
    const float* __restrict__ b2ihp, const float* __restrict__ b2hhp,
    const float* __restrict__ h01, const float* __restrict__ c01,
    const float* __restrict__ h02, const float* __restrict__ c02,
    float* __restrict__ outseq2,
    float* __restrict__ hf1, float* __restrict__ cf1,
    float* __restrict__ hf2, float* __restrict__ cf2,
    int S, int mode)
{
    __shared__ __align__(16) _Float16 A1[2 * 16 * PADH];       // [plane][row][k]
    __shared__ __align__(16) _Float16 A2[2][2 * 16 * PADH];    // [buf][plane][row][k]
    __shared__ __align__(16) float gb1[ROWS * GBS];            // [row][gatecol]
    __shared__ __align__(16) float gb2[ROWS * GBS];

    const int tid  = threadIdx.x;
    const int w    = tid >> 6;          // 0..15
    const int l    = tid & 63;
    const int lrow = l & 15;
    const int lkg  = l >> 4;
    const int row0 = blockIdx.x * ROWS;

    const bool isL2w = (w >= 8);
    const int  wl    = w & 7;           // col-group within the layer

    // --- this wave's layer weights (16 half8) -------------------------------
    const _Float16* wsrc = isL2w ? w2half : w1half;
    const float* bihp = isL2w ? b2ihp : b1ihp;
    const float* bhhp = isL2w ? b2hhp : b1hhp;
    half8 whi[4][2], wlo[4][2];
    #pragma unroll
    for (int kt = 0; kt < 4; ++kt)
        #pragma unroll
        for (int nt = 0; nt < 2; ++nt) {
            const int col = wl * 32 + nt * 16 + lrow;
            const size_t off = (size_t)col * 128 + kt * 32 + lkg * 8;
            whi[kt][nt] = *(const half8*)&wsrc[off];
            wlo[kt][nt] = *(const half8*)&wsrc[32768 + off];
        }
    float bs[2];
    #pragma unroll
    for (int nt = 0; nt < 2; ++nt) {
        const int col = wl * 32 + nt * 16 + lrow;
        bs[nt] = bihp[col] + bhhp[col];
    }

    // cell/staging map within own 512-thread group: col ju, rows ru & ru+8
    const int t2 = tid & 511;
    const int ju = t2 & 63, ru = t2 >> 6;

    // ---- prologue ----------------------------------------------------------
    float cst[2], hlast[2] = {0.f, 0.f};
    if (!isL2w) {
        #pragma unroll
        for (int r2 = 0; r2 < 2; ++r2) {
            const int r = ru + 8 * r2;
            // x(0)
            const float* p0 = (mode == 1) ? (in0 + (size_t)(row0 + r) * 64)
                                          : (inseq + (size_t)(row0 + r) * S * 64);
            float v = p0[ju];
            _Float16 xh = (_Float16)v;
            A1[r * PADH + ju] = xh;
            A1[16 * PADH + r * PADH + ju] = (_Float16)((v - (float)xh) * 2048.f);
            // h01
            float hv = h01 ? h01[(size_t)(row0 + r) * 64 + ju] : 0.f;
            _Float16 hh = (_Float16)hv;
            A1[r * PADH + 64 + ju] = hh;
            A1[16 * PADH + r * PADH + 64 + ju] = (_Float16)((hv - (float)hh) * 2048.f);
            cst[r2] = c01 ? c01[(size_t)(row0 + r) * 64 + ju] : 0.f;
        }
    } else {
        #pragma unroll
        for (int r2 = 0; r2 < 2; ++r2) {
            const int r = ru + 8 * r2;
            // h02 -> A2buf[0] h-part (consumed by L2G(0))
            float hv = h02 ? h02[(size_t)(row0 + r) * 64 + ju] : 0.f;
            _Float16 hh = (_Float16)hv;
            A2[0][r * PADH + 64 + ju] = hh;
            A2[0][16 * PADH + r * PADH + 64 + ju] = (_Float16)((hv - (float)hh) * 2048.f);
            cst[r2] = c02 ? c02[(size_t)(row0 + r) * 64 + ju] : 0.f;
        }
    }

    const int aoff = lrow * PADH + lkg * 8;

    for (int i = 0; i <= S + 1; ++i) {
        __syncthreads();   // ---- phase A: A1/gb2 ready ----
        float xn[2];
        if (!isL2w) {
            if (i + 1 < S) {   // prefetch x(i+1), staged in phase B
                #pragma unroll
                for (int r2 = 0; r2 < 2; ++r2) {
                    const int r = ru + 8 * r2;
                    const float* pn = (mode == 1)
                        ? (inseq + ((size_t)(row0 + r) * S + i) * 64)       // target[i]
                        : (inseq + ((size_t)(row0 + r) * S + (i + 1)) * 64);
                    xn[r2] = pn[ju];
                }
            }
            if (i < S) {   // L1 GEMM: gb1 = A1 @ W1^T
                f32x4 a0[2], a1[2];
                #pragma unroll
                for (int nt = 0; nt < 2; ++nt) {
                    a0[nt] = (f32x4){bs[nt], bs[nt], bs[nt], bs[nt]};
                    a1[nt] = (f32x4){0.f, 0.f, 0.f, 0.f};
                }
                #pragma unroll
                for (int kt = 0; kt < 4; ++kt) {
                    half8 ah = *(const half8*)&A1[aoff + kt * 32];
                    half8 al = *(const half8*)&A1[16 * PADH + aoff + kt * 32];
                    #pragma unroll
                    for (int nt = 0; nt < 2; ++nt) {
                        a0[nt] = __builtin_amdgcn_mfma_f32_16x16x32_f16(ah, whi[kt][nt], a0[nt], 0, 0, 0);
                        a1[nt] = __builtin_amdgcn_mfma_f32_16x16x32_f16(ah, wlo[kt][nt], a1[nt], 0, 0, 0);
                        a1[nt] = __builtin_amdgcn_mfma_f32_16x16x32_f16(al, whi[kt][nt], a1[nt], 0, 0, 0);
                    }
                }
                #pragma unroll
                for (int nt = 0; nt < 2; ++nt) {
                    f32x4 g = a0[nt] + a1[nt] * IC_;
                    const int col = wl * 32 + nt * 16 + lrow;
                    #pragma unroll
                    for (int q = 0; q < 4; ++q)
                        gb1[(lkg * 4 + q) * GBS + col] = g[q];
                }
            }
        } else {
            const int j = i - 2;
            if (j >= 0 && j < S) {   // L2 cell: h2(j) -> A2buf[(j+1)&1] + out
                _Float16* Ad = A2[(j + 1) & 1];
                #pragma unroll
                for (int r2 = 0; r2 < 2; ++r2) {
                    const int r = ru + 8 * r2;
                    float gi = gb2[r * GBS +   0 + ju];
                    float gf = gb2[r * GBS +  64 + ju];
                    float gg = gb2[r * GBS + 128 + ju];
                    float go = gb2[r * GBS + 192 + ju];
                    cst[r2] = fsig(gf) * cst[r2] + fsig(gi) * ftanh(gg);
                    float hv = fsig(go) * ftanh(cst[r2]);
                    hlast[r2] = hv;
                    _Float16 hh = (_Float16)hv;
                    Ad[r * PADH + 64 + ju] = hh;
                    Ad[16 * PADH + r * PADH + 64 + ju] =
                        (_Float16)((hv - (float)hh) * 2048.f);
                    outseq2[((size_t)(row0 + r) * S + j) * 64 + ju] = hv;
                }
            }
        }
        __syncthreads();   // ---- phase B: gb1 ready; A2buf parities settled ----
        if (!isL2w) {
            if (i < S) {   // L1 cell: h1(i) -> A1 h-part + A2buf[i&1] x-part
                _Float16* Ad = A2[i & 1];
                #pragma unroll
                for (int r2 = 0; r2 < 2; ++r2) {
                    const int r = ru + 8 * r2;
                    float gi = gb1[r * GBS +   0 + ju];
                    float gf = gb1[r * GBS +  64 + ju];
                    float gg = gb1[r * GBS + 128 + ju];
                    float go = gb1[r * GBS + 192 + ju];
                    cst[r2] = fsig(gf) * cst[r2] + fsig(gi) * ftanh(gg);
                    float hv = fsig(go) * ftanh(cst[r2]);
                    hlast[r2] = hv;
                    _Float16 hh = (_Float16)hv;
                    _Float16 hlo = (_Float16)((hv - (float)hh) * 2048.f);
                    A1[r * PADH + 64 + ju] = hh;
                    A1[16 * PADH + r * PADH + 64 + ju] = hlo;
                    Ad[r * PADH + ju] = hh;
                    Ad[16 * PADH + r * PADH + ju] = hlo;
                }
            }
            if (i + 1 < S) {   // stage x(i+1) into A1 x-part
                #pragma unroll
                for (int r2 = 0; r2 < 2; ++r2) {
                    const int r = ru + 8 * r2;
                    _Float16 xh = (_Float16)xn[r2];
                    A1[r * PADH + ju] = xh;
                    A1[16 * PADH + r * PADH + ju] =
                        (_Float16)((xn[r2] - (float)xh) * 2048.f);
                }
            }
        } else {
            const int j2 = i - 1;
            if (j2 >= 0 && j2 < S) {   // L2 GEMM from A2buf[j2&1] -> gb2
                const _Float16* As = A2[j2 & 1];
                f32x4 a0[2], a1[2];
                #pragma unroll
                for (int nt = 0; nt < 2; ++nt) {
                    a0[nt] = (f32x4){bs[nt], bs[nt], bs[nt], bs[nt]};
                    a1[nt] = (f32x4){0.f, 0.f, 0.f, 0.f};
                }
                #pragma unroll
                for (int kt = 0; kt < 4; ++kt) {
                    half8 ah = *(const half8*)&As[aoff + kt * 32];
                    half8 al = *(const half8*)&As[16 * PADH + aoff + kt * 32];
                    #pragma unroll
                    for (int nt = 0; nt < 2; ++nt) {
                        a0[nt] = __builtin_amdgcn_mfma_f32_16x16x32_f16(ah, whi[kt][nt], a0[nt], 0, 0, 0);
                        a1[nt] = __builtin_amdgcn_mfma_f32_16x16x32_f16(ah, wlo[kt][nt], a1[nt], 0, 0, 0);
                        a1[nt] = __builtin_amdgcn_mfma_f32_16x16x32_f16(al, whi[kt][nt], a1[nt], 0, 0, 0);
                    }
                }
                #pragma unroll
                for (int nt = 0; nt < 2; ++nt) {
                    f32x4 g = a0[nt] + a1[nt] * IC_;
                    const int col = wl * 32 + nt * 16 + lrow;
                    #pragma unroll
                    for (int q = 0; q < 4; ++q)
                        gb2[(lkg * 4 + q) * GBS + col] = g[q];
                }
            }
        }
    }
    if (hf1) {
        float* hdst = isL2w ? hf2 : hf1;
        float* cdst = isL2w ? cf2 : cf1;
        #pragma unroll
        for (int r2 = 0; r2 < 2; ++r2) {
            const int r = ru + 8 * r2;
            hdst[(size_t)(row0 + r) * 64 + ju] = hlast[r2];
            cdst[(size_t)(row0 + r) * 64 + ju] = cst[r2];
        }
    }
}

// ---------------------------------------------------------------------------
// Helper: stage a fp32 row-block into hi/lo fp16 LDS planes [R][72] (attn0)
// ---------------------------------------------------------------------------
__device__ __forceinline__ void stage_split(const float* __restrict__ src,
                                            _Float16* dst, int plane,
                                            int row, int c0) {
    #pragma unroll
    for (int u = 0; u < 4; ++u) {
        float4 v = *(const float4*)(src + u * 4);
        half4 hi, lo;
        hi[0] = (_Float16)v.x; lo[0] = (_Float16)((v.x - (float)hi[0]) * 2048.f);
        hi[1] = (_Float16)v.y; lo[1] = (_Float16)((v.y - (float)hi[1]) * 2048.f);
        hi[2] = (_Float16)v.z; lo[2] = (_Float16)((v.z - (float)hi[2]) * 2048.f);
        hi[3] = (_Float16)v.w; lo[3] = (_Float16)((v.w - (float)hi[3]) * 2048.f);
        *(half4*)&dst[row * 72 + c0 + u * 4] = hi;
        *(half4*)&dst[plane + row * 72 + c0 + u * 4] = lo;
    }
}

// ---------------------------------------------------------------------------
// Self-attention, last query only (round-3 known-good).
// ---------------------------------------------------------------------------
__global__ __launch_bounds__(256) void attn0_mfma(
    const float* __restrict__ encout,
    const _Float16* __restrict__ wqkvh,
    const float* __restrict__ bqkv,
    const float* __restrict__ Wqkv,
    const float* __restrict__ Wo,
    const float* __restrict__ bo,
    float* __restrict__ a0last)
{
    __shared__ __align__(16) _Float16 E16[2 * 4608];
    __shared__ __align__(16) _Float16 K16[2 * 4608];
    __shared__ __align__(16) _Float16 V16[4608];
    __shared__ float qv[64];
    __shared__ float wrow[4 * 68];
    __shared__ float ov[64];

    const int b = blockIdx.x, tid = threadIdx.x;
    const int w = tid >> 6, l = tid & 63, lr = l & 15, lkg = l >> 4;

    {
        int row = tid >> 2, c0 = (tid & 3) * 16;
        stage_split(encout + (size_t)b * 4096 + row * 64 + c0, E16, 4608, row, c0);
    }
    __syncthreads();

    for (int tt = w; tt < 8; tt += 4) {
        const int kind = (tt < 4) ? 0 : 1;
        const int mrow = (kind ? tt - 4 : tt) * 16;
        const int wrowB = kind ? 128 : 64;
        half8 ah[2], al[2];
        #pragma unroll
        for (int kt = 0; kt < 2; ++kt) {
            int ao = (mrow + lr) * 72 + kt * 32 + lkg * 8;
            ah[kt] = *(const half8*)&E16[ao];
            al[kt] = *(const half8*)&E16[4608 + ao];
        }
        #pragma unroll
        for (int nt = 0; nt < 4; ++nt) {
            const int col = nt * 16 + lr;
            const float bv = bqkv[wrowB + col];
            f32x4 a0 = (f32x4){bv, bv, bv, bv};
            f32x4 a1 = (f32x4){0.f, 0.f, 0.f, 0.f};
            #pragma unroll
            for (int kt = 0; kt < 2; ++kt) {
                const _Float16* wp = wqkvh + (size_t)(wrowB + col) * 64 + kt * 32 + lkg * 8;
                half8 bh = *(const half8*)wp;
                half8 bl = *(const half8*)(wp + 12288);
                a0 = __builtin_amdgcn_mfma_f32_16x16x32_f16(ah[kt], bh, a0, 0, 0, 0);
                a1 = __builtin_amdgcn_mfma_f32_16x16x32_f16(ah[kt], bl, a1, 0, 0, 0);
                a1 = __builtin_amdgcn_mfma_f32_16x16x32_f16(al[kt], bh, a1, 0, 0, 0);
            }
            #pragma unroll
            for (int i = 0; i < 4; ++i) {
                float g = a0[i] + a1[i] * IC_;
                int r = mrow + lkg * 4 + i;
                if (kind == 0) {
                    _Float16 gh = (_Float16)g;
                    K16[r * 72 + col] = gh;
                    K16[4608 + r * 72 + col] = (_Float16)((g - (float)gh) * 2048.f);
                } else {
                    V16[r * 72 + col] = (_Float16)g;
                }
            }
        }
    }
    if (w == 3) {
        float a = bqkv[l];
        for (int k = 0; k < 64; ++k) {
            float e = (float)E16[63 * 72 + k] + (float)E16[4608 + 63 * 72 + k] * IC_;
            a += e * Wqkv[l * 64 + k];
        }
        qv[l] = a;
    }
    __syncthreads();

    {
        const int h = tid >> 6, kv = tid & 63;
        float s = 0.f;
        #pragma unroll
        for (int d = 0; d < 16; ++d) {
            float kk = (float)K16[kv * 72 + h * 16 + d]
                     + (float)K16[4608 + kv * 72 + h * 16 + d] * IC_;
            s += qv[h * 16 + d] * kk;
        }
        s *= 0.25f;
        float m = s;
        #pragma unroll
        for (int off = 32; off; off >>= 1) m = fmaxf(m, __shfl_xor(m, off));
        float e = __expf(s - m);
        float sum = e;
        #pragma unroll
        for (int off = 32; off; off >>= 1) sum += __shfl_xor(sum, off);
        wrow[h * 68 + kv] = e / sum;
    }
    __syncthreads();
    if (tid < 64) {
        const int h = tid >> 4, d = tid & 15;
        float o = 0.f;
        for (int kv = 0; kv < 64; ++kv)
            o += wrow[h * 68 + kv] * (float)V16[kv * 72 + h * 16 + d];
        ov[tid] = o;
    }
    __syncthreads();
    if (tid < 64) {
        float a = bo[tid];
        for (int k = 0; k < 64; ++k) a += ov[k] * Wo[tid * 64 + k];
        a0last[(size_t)b * 64 + tid] = a;
    }
}

// ---------------------------------------------------------------------------
// Cross-attention v2 (round-4 known-good): one b per block, S^T scores,
// no atomics, 4 barriers, 40960 B dynamic LDS.
// ---------------------------------------------------------------------------
__global__ __launch_bounds__(256, 4) void cross_attn_v2(
    const float* __restrict__ encout, const float* __restrict__ decout,
    const _Float16* __restrict__ wqkvh, const float* __restrict__ bqkv,
    _Float16* __restrict__ AOg, float* __restrict__ attnw)
{
    extern __shared__ __align__(16) char smem[];
    _Float16* E  = (_Float16*)(smem);
    _Float16* D  = (_Float16*)(smem + 9216);
    _Float16* K  = (_Float16*)(smem + 16128);
    _Float16* Q  = (_Float16*)(smem + 25344);
    _Float16* VT = (_Float16*)(smem + 32256);

    const int b = blockIdx.x, tid = threadIdx.x;
    const int w = tid >> 6, l = tid & 63, lr = l & 15, lkg = l >> 4;
    const int h = w;

    {
        int row = tid >> 2, c0 = (tid & 3) * 16;
        const float* ep = encout + (size_t)b * 4096 + row * 64 + c0;
        half8 v0, v1;
        #pragma unroll
        for (int j = 0; j < 8; ++j) v0[j] = (_Float16)ep[j];
        #pragma unroll
        for (int j = 0; j < 8; ++j) v1[j] = (_Float16)ep[8 + j];
        *(half8*)&E[row * 72 + c0] = v0;
        *(half8*)&E[row * 72 + c0 + 8] = v1;
        if (row < 48) {
            const float* dp = decout + (size_t)b * 3072 + row * 64 + c0;
            half8 u0, u1;
            #pragma unroll
            for (int j = 0; j < 8; ++j) u0[j] = (_Float16)dp[j];
            #pragma unroll
            for (int j = 0; j < 8; ++j) u1[j] = (_Float16)dp[8 + j];
            *(half8*)&D[row * 72 + c0] = u0;
            *(half8*)&D[row * 72 + c0 + 8] = u1;
        }
    }
    __syncthreads();

    for (int tt = w; tt < 11; tt += 4) {
        const int kind = (tt < 4) ? 0 : ((tt < 8) ? 1 : 2);
        const int mrow = ((kind == 0) ? tt : (kind == 1) ? tt - 4 : tt - 8) * 16;
        const int wrowB = (kind == 0) ? 64 : ((kind == 1) ? 128 : 0);
        const _Float16* S = (kind == 2) ? D : E;
        half8 ah[2];
        #pragma unroll
        for (int kt = 0; kt < 2; ++kt)
            ah[kt] = *(const half8*)&S[(mrow + lr) * 72 + kt * 32 + lkg * 8];
        #pragma unroll
        for (int nt = 0; nt < 4; ++nt) {
            const int col = nt * 16 + lr;
            const float bv = bqkv[wrowB + col];
            f32x4 a0 = (f32x4){bv, bv, bv, bv};
            #pragma unroll
            for (int kt = 0; kt < 2; ++kt) {
                half8 bh = *(const half8*)&wqkvh[(size_t)(wrowB + col) * 64 + kt * 32 + lkg * 8];
                a0 = __builtin_amdgcn_mfma_f32_16x16x32_f16(ah[kt], bh, a0, 0, 0, 0);
            }
            if (kind == 1) {
                half4 p;
                #pragma unroll
                for (int i = 0; i < 4; ++i) p[i] = (_Float16)a0[i];
                *(half4*)&VT[col * 68 + mrow + lkg * 4] = p;
            } else {
                _Float16* dst = (kind == 0) ? K : Q;
                #pragma unroll
                for (int i = 0; i < 4; ++i)
                    dst[(mrow + lkg * 4 + i) * 72 + col] = (_Float16)a0[i];
            }
        }
    }
    __syncthreads();

    const half8 z = {0, 0, 0, 0, 0, 0, 0, 0};
    half8 ka[4], qb[3];
    #pragma unroll
    for (int kvt = 0; kvt < 4; ++kvt)
        ka[kvt] = (lkg < 2) ? *(const half8*)&K[(kvt * 16 + lr) * 72 + h * 16 + lkg * 8] : z;
    #pragma unroll
    for (int qt = 0; qt < 3; ++qt)
        qb[qt] = (lkg < 2) ? *(const half8*)&Q[(qt * 16 + lr) * 72 + h * 16 + lkg * 8] : z;
    __syncthreads();

    _Float16* strip = (_Float16*)(smem + ((h == 0) ? 0 : (h == 1) ? 9216
                                        : (h == 2) ? 16128 : 25344));
    {
        f32x4 s[3][4];
        #pragma unroll
        for (int qt = 0; qt < 3; ++qt) {
            #pragma unroll
            for (int kvt = 0; kvt < 4; ++kvt) {
                f32x4 a0 = (f32x4){0.f, 0.f, 0.f, 0.f};
                a0 = __builtin_amdgcn_mfma_f32_16x16x32_f16(ka[kvt], qb[qt], a0, 0, 0, 0);
                s[qt][kvt] = a0 * 0.25f;
            }
            float m = s[qt][0][0];
            #pragma unroll
            for (int kvt = 0; kvt < 4; ++kvt)
                #pragma unroll
                for (int i = 0; i < 4; ++i) m = fmaxf(m, s[qt][kvt][i]);
            m = fmaxf(m, __shfl_xor(m, 16));
            m = fmaxf(m, __shfl_xor(m, 32));
            float sum = 0.f;
            #pragma unroll
            for (int kvt = 0; kvt < 4; ++kvt)
                #pragma unroll
                for (int i = 0; i < 4; ++i) {
                    float e = __expf(s[qt][kvt][i] - m);
                    s[qt][kvt][i] = e;
                    sum += e;
                }
            sum += __shfl_xor(sum, 16);
            sum += __shfl_xor(sum, 32);
            const float r = 1.0f / sum;
            #pragma unroll
            for (int kvt = 0; kvt < 4; ++kvt) {
                half4 p;
                #pragma unroll
                for (int i = 0; i < 4; ++i) p[i] = (_Float16)(s[qt][kvt][i] * r);
                *(half4*)&strip[(qt * 16 + lr) * 72 + kvt * 16 + lkg * 4] = p;
            }
        }
    }
    {
        half8 vb[2];
        #pragma unroll
        for (int kt = 0; kt < 2; ++kt) {
            half4 lo4 = *(const half4*)&VT[(h * 16 + lr) * 68 + kt * 32 + lkg * 8];
            half4 hi4 = *(const half4*)&VT[(h * 16 + lr) * 68 + kt * 32 + lkg * 8 + 4];
            #pragma unroll
            for (int j = 0; j < 4; ++j) { vb[kt][j] = lo4[j]; vb[kt][4 + j] = hi4[j]; }
        }
        #pragma unroll
        for (int qt = 0; qt < 3; ++qt) {
            f32x4 acc = (f32x4){0.f, 0.f, 0.f, 0.f};
            #pragma unroll
            for (int kt = 0; kt < 2; ++kt) {
                half8 wa = *(const half8*)&strip[(qt * 16 + lr) * 72 + kt * 32 + lkg * 8];
                acc = __builtin_amdgcn_mfma_f32_16x16x32_f16(wa, vb[kt], acc, 0, 0, 0);
            }
            #pragma unroll
            for (int i = 0; i < 4; ++i)
                AOg[((size_t)b * 48 + qt * 16 + lkg * 4 + i) * 64 + h * 16 + lr] =
                    (_Float16)acc[i];
        }
    }
    __syncthreads();

    {
        const _Float16* s0 = (const _Float16*)(smem);
        const _Float16* s1 = (const _Float16*)(smem + 9216);
        const _Float16* s2 = (const _Float16*)(smem + 16128);
        const _Float16* s3 = (const _Float16*)(smem + 25344);
        #pragma unroll
        for (int it = 0; it < 12; ++it) {
            int idx = tid + it * 256;
            int o = (idx >> 6) * 72 + (idx & 63);
            attnw[(size_t)b * 3072 + idx] =
                0.25f * ((float)s0[o] + (float)s1[o] + (float)s2[o] + (float)s3[o]);
        }
    }
}

// ---------------------------------------------------------------------------
// Batched out-proj + FC1(relu) + FC2. 64 rows/block, zero barriers.
// ---------------------------------------------------------------------------
__global__ __launch_bounds__(256) void proj_fc_kernel(
    const _Float16* __restrict__ AOg,
    const _Float16* __restrict__ woh, const float* __restrict__ bo,
    const _Float16* __restrict__ w1h, const float* __restrict__ b1,
    const float* __restrict__ W2,     const float* __restrict__ b2,
    float* __restrict__ pred)
{
    __shared__ __align__(16) _Float16 obuf[4][16 * 72];
    __shared__ float h1buf[4][16 * 36];
    const int tid = threadIdx.x;
    const int w = tid >> 6, l = tid & 63, lr = l & 15, lkg = l >> 4;
    const size_t r0 = (size_t)blockIdx.x * 64 + w * 16;

    half8 ah[2];
    #pragma unroll
    for (int kt = 0; kt < 2; ++kt)
        ah[kt] = *(const half8*)&AOg[(r0 + lr) * 64 + kt * 32 + lkg * 8];
    #pragma unroll
    for (int nt = 0; nt < 4; ++nt) {
        const int col = nt * 16 + lr;
        const float bv = bo[col];
        f32x4 a0 = (f32x4){bv, bv, bv, bv};
        #pragma unroll
        for (int kt = 0; kt < 2; ++kt) {
            half8 bh = *(const half8*)&woh[(size_t)col * 64 + kt * 32 + lkg * 8];
            a0 = __builtin_amdgcn_mfma_f32_16x16x32_f16(ah[kt], bh, a0, 0, 0, 0);
        }
        #pragma unroll
        for (int i = 0; i < 4; ++i)
            obuf[w][(lkg * 4 + i) * 72 + col] = (_Float16)a0[i];
    }
    half8 oh[2];
    #pragma unroll
    for (int kt = 0; kt < 2; ++kt)
        oh[kt] = *(const half8*)&obuf[w][lr * 72 + kt * 32 + lkg * 8];
    #pragma unroll
    for (int nt = 0; nt < 2; ++nt) {
        const int m = nt * 16 + lr;
        const float bv = b1[m];
        f32x4 a0 = (f32x4){bv, bv, bv, bv};
        #pragma unroll
        for (int kt = 0; kt < 2; ++kt) {
            half8 bh = *(const half8*)&w1h[(size_t)m * 64 + kt * 32 + lkg * 8];
            a0 = __builtin_amdgcn_mfma_f32_16x16x32_f16(oh[kt], bh, a0, 0, 0, 0);
        }
        #pragma unroll
        for (int i = 0; i < 4; ++i)
            h1buf[w][(lkg * 4 + i) * 36 + m] = fmaxf(a0[i], 0.f);
    }
    if (l < 48) {
        const int q = l / 3, n = l - 3 * q;
        float a = b2[n];
        #pragma unroll
        for (int m2 = 0; m2 < 32; ++m2)
            a += h1buf[w][q * 36 + m2] * W2[n * 32 + m2];
        pred[(r0 + q) * 3 + n] = a;
    }
}

// ---------------------------------------------------------------------------
extern "C" void kernel_launch(void* const* d_in, const int* in_sizes, int n_in,
                              void* d_out, int out_size, void* d_ws, size_t ws_size,
                              hipStream_t stream) {
    const float* x      = (const float*)d_in[0];
    const float* target = (const float*)d_in[1];
    const float* eWih0 = (const float*)d_in[2],  *eWhh0 = (const float*)d_in[3];
    const float* ebih0 = (const float*)d_in[4],  *ebhh0 = (const float*)d_in[5];
    const float* eWih1 = (const float*)d_in[6],  *eWhh1 = (const float*)d_in[7];
    const float* ebih1 = (const float*)d_in[8],  *ebhh1 = (const float*)d_in[9];
    const float* dWih0 = (const float*)d_in[10], *dWhh0 = (const float*)d_in[11];
    const float* dbih0 = (const float*)d_in[12], *dbhh0 = (const float*)d_in[13];
    const float* dWih1 = (const float*)d_in[14], *dWhh1 = (const float*)d_in[15];
    const float* dbih1 = (const float*)d_in[16], *dbhh1 = (const float*)d_in[17];
    const float* Wqkv = (const float*)d_in[18], *bqkv = (const float*)d_in[19];
    const float* Wo   = (const float*)d_in[20], *bo   = (const float*)d_in[21];
    const float* W1   = (const float*)d_in[22], *b1   = (const float*)d_in[23];
    const float* W2   = (const float*)d_in[24], *b2   = (const float*)d_in[25];

    float* ws = (float*)d_ws;
    float* hseq1  = ws;                                   // AOg alias region
    float* encout = hseq1  + (size_t)B_ * L_ * H_;
    float* decout = encout + (size_t)B_ * L_ * H_;
    float* a0last = decout + (size_t)B_ * T_ * H_;
    float* hfin   = a0last + (size_t)B_ * H_;
    float* cfin   = hfin   + (size_t)2 * B_ * H_;
    float* wtg    = cfin   + (size_t)2 * B_ * H_;
    float* auxw   = wtg    + (size_t)4 * 32768;

    _Float16* wh0 = (_Float16*)(wtg);
    _Float16* wh1 = wh0 + 65536;
    _Float16* wh2 = wh1 + 65536;
    _Float16* wh3 = wh2 + 65536;
    _Float16* wqkvh = (_Float16*)auxw;        // [2][192][64]
    _Float16* woh   = wqkvh + 24576;          // [2][64][64]
    _Float16* w1h   = woh + 8192;             // [2][32][64]
    _Float16* AOg   = (_Float16*)hseq1;

    float* pred  = (float*)d_out;
    float* attnw = pred + (size_t)B_ * T_ * 3;

    transpose_w_kernel<<<64, 256, 0, stream>>>(eWih0, eWhh0, wh0);
    transpose_w_kernel<<<64, 256, 0, stream>>>(eWih1, eWhh1, wh1);
    transpose_w_kernel<<<64, 256, 0, stream>>>(dWih0, dWhh0, wh2);
    transpose_w_kernel<<<64, 256, 0, stream>>>(dWih1, dWhh1, wh3);
    split_aux_kernel<<<72, 256, 0, stream>>>(Wqkv, Wo, W1, wqkvh, woh, w1h);

    // fused encoder (anti-phased layer-split); 256 blocks x 1024 thr
    lstm2_mfma_kernel<<<B_ / ROWS, 1024, 0, stream>>>(
        x, nullptr, wh0, ebih0, ebhh0, wh1, ebih1, ebhh1,
        nullptr, nullptr, nullptr, nullptr,
        encout, hfin, cfin, hfin + (size_t)B_ * H_, cfin + (size_t)B_ * H_, L_, 0);
    // self-attn, last query
    attn0_mfma<<<B_, 256, 0, stream>>>(encout, wqkvh, bqkv, Wqkv, Wo, bo, a0last);
    // fused decoder
    lstm2_mfma_kernel<<<B_ / ROWS, 1024, 0, stream>>>(
        target, a0last, wh2, dbih0, dbhh0, wh3, dbih1, dbhh1,
        hfin, cfin, hfin + (size_t)B_ * H_, cfin + (size_t)B_ * H_,
        decout, nullptr, nullptr, nullptr, nullptr, T_, 1);
    // cross-attention -> AOg, attnw
    cross_attn_v2<<<B_, 256, 40960, stream>>>(
        encout, decout, wqkvh, bqkv, AOg, attnw);
    // out-proj + FC1 + FC2 -> pred
    proj_fc_kernel<<<(B_ * T_) / 64, 256, 0, stream>>>(
        AOg, woh, bo, w1h, b1, W2, b2, pred);
}

// Round 10
// 395.050 us; speedup vs baseline: 1.2641x; 1.2641x over previous
//
#include <hip/hip_runtime.h>
#include <hip/hip_bf16.h>
#include <cstddef>

// ---------------------------------------------------------------------------
// LSTMSeq2Seq: B=4096, L=64, T=48, H=64, NH=4, HD=16, NQ=3
// Round 10: gate-aligned LSTM tiling — wave owns all 4 gates of 16 h-cols,
// so the cell update is lane-local in the MFMA accumulators. No gate staging
// LDS, ONE lgkm-only barrier per step. A-state double-buffered.
// ---------------------------------------------------------------------------

#define B_   4096
#define L_   64
#define T_   48
#define H_   64
#define ROWS 16      // batch rows per LSTM block
#define PADH 136     // LSTM A row pad (halves)

using half8  = __attribute__((ext_vector_type(8))) _Float16;
using half4  = __attribute__((ext_vector_type(4))) _Float16;
using f32x4  = __attribute__((ext_vector_type(4))) float;

#define IC_ 4.8828125e-4f   // 2^-11

// native-rate transcendentals (v_exp_f32 + v_rcp_f32); overflow-safe forms
__device__ __forceinline__ float fsig(float x) {
    return __builtin_amdgcn_rcpf(1.0f + __expf(-x));
}
__device__ __forceinline__ float ftanh(float x) {
    float e = __expf(-2.0f * fabsf(x));            // e in (0,1], never overflows
    float r = (1.0f - e) * __builtin_amdgcn_rcpf(1.0f + e);
    return copysignf(r, x);
}

// ---------------------------------------------------------------------------
// LSTM weight split (one-time): whalf[split][gate_row 256][k 128]
// ---------------------------------------------------------------------------
__global__ void transpose_w_kernel(const float* __restrict__ Wih,
                                   const float* __restrict__ Whh,
                                   _Float16* __restrict__ out) {
    int idx = blockIdx.x * 256 + threadIdx.x;
    if (idx >= 16384) return;
    int r = idx >> 6, k = idx & 63;
    float wi = Wih[idx];
    _Float16 hi = (_Float16)wi;
    out[r * 128 + k] = hi;
    out[32768 + r * 128 + k] = (_Float16)((wi - (float)hi) * 2048.0f);
    float wh = Whh[idx];
    hi = (_Float16)wh;
    out[r * 128 + 64 + k] = hi;
    out[32768 + r * 128 + 64 + k] = (_Float16)((wh - (float)hi) * 2048.0f);
}

// Attention weight splits: wqkvh[2][192][64], woh[2][64][64], w1h[2][32][64]
__global__ void split_aux_kernel(const float* __restrict__ Wqkv,
                                 const float* __restrict__ Wo,
                                 const float* __restrict__ W1,
                                 _Float16* __restrict__ wqkvh,
                                 _Float16* __restrict__ woh,
                                 _Float16* __restrict__ w1h) {
    int idx = blockIdx.x * 256 + threadIdx.x;
    if (idx < 12288) {
        float v = Wqkv[idx]; _Float16 h = (_Float16)v;
        wqkvh[idx] = h; wqkvh[12288 + idx] = (_Float16)((v - (float)h) * 2048.f);
    } else if (idx < 16384) {
        int i = idx - 12288;
        float v = Wo[i]; _Float16 h = (_Float16)v;
        woh[i] = h; woh[4096 + i] = (_Float16)((v - (float)h) * 2048.f);
    } else if (idx < 18432) {
        int i = idx - 16384;
        float v = W1[i]; _Float16 h = (_Float16)v;
        w1h[i] = h; w1h[2048 + i] = (_Float16)((v - (float)h) * 2048.f);
    }
}

// ---------------------------------------------------------------------------
// Fused 2-layer LSTM, gate-aligned. 256 blocks x 512 threads (8 waves).
// Waves 0-3: layer 1; waves 4-7: layer 2 (skewed one step).
// Wave wl owns h-cols [wl*16, wl*16+16) via 4 N-tiles = the 4 gates at
// cols g*64 + wl*16. After GEMM, lane holds (i,f,g,o) for its (row, hcol)
// in acc[g][q] -> cell is register-local. A1/A2 double-buffered by parity;
// ONE raw barrier (lgkmcnt-only: global stores don't drain) per iteration.
// launch_bounds(512,2): 256-reg cap (128 weight regs + ~70 live; NO (.,4)
// cap — that spilled weights in round 6).
// ---------------------------------------------------------------------------
__global__ __launch_bounds__(512, 2) void lstm2_mfma_kernel(
    const float* __restrict__ inseq,
    const float* __restrict__ in0,
    const _Float16* __restrict__ w1half,
    const float* __restrict__ b1ihp, const float* __restrict__ b1hhp,
    const _Float16* __restrict__ w2half,
    const float* __restrict__ b2ihp, const float* __restrict__ b2hhp,
    const float* __restrict__ h01, const float* __restrict__ c01,
    const float* __restrict__ h02, const float* __restrict__ c02,
    float* __restrict__ outseq2,
    float* __restrict__ hf1, float* __restrict__ cf1,
    float* __restrict__ hf2, float* __restrict__ cf2,
    int S, int mode)
{
    __shared__ __align__(16) _Float16 A1[2][2 * 16 * PADH];   // [buf][plane][row][k]
    __shared__ __align__(16) _Float16 A2[2][2 * 16 * PADH];

    const int tid  = threadIdx.x;
    const int w    = tid >> 6;          // 0..7
    const int lrow = tid & 15;
    const int lkg  = (tid >> 4) & 3;
    const int row0 = blockIdx.x * ROWS;

    const bool isL2w = (w >= 4);
    const int  wl    = w & 3;
    const int  hcol  = wl * 16 + lrow;  // this lane's h/x column (0..63)

    const _Float16* wsrc = isL2w ? w2half : w1half;
    const float* bihp = isL2w ? b2ihp : b1ihp;
    const float* bhhp = isL2w ? b2hhp : b1hhp;

    // weights: 4 gates x 4 k-tiles x 2 splits = 32 half8 (128 regs)
    half8 whi[4][4], wlo[4][4];
    #pragma unroll
    for (int kt = 0; kt < 4; ++kt)
        #pragma unroll
        for (int g = 0; g < 4; ++g) {
            const int col = g * 64 + hcol;
            const size_t off = (size_t)col * 128 + kt * 32 + lkg * 8;
            whi[kt][g] = *(const half8*)&wsrc[off];
            wlo[kt][g] = *(const half8*)&wsrc[32768 + off];
        }
    float bsv[4];
    #pragma unroll
    for (int g = 0; g < 4; ++g)
        bsv[g] = bihp[g * 64 + hcol] + bhhp[g * 64 + hcol];

    float c[4], hlast[4] = {0.f, 0.f, 0.f, 0.f};

    // ---- prologue ----------------------------------------------------------
    if (!isL2w) {
        #pragma unroll
        for (int q = 0; q < 4; ++q) {
            const int r = 4 * lkg + q;
            const float* p0 = (mode == 1) ? (in0 + (size_t)(row0 + r) * 64)
                                          : (inseq + (size_t)(row0 + r) * S * 64);
            float v = p0[hcol];
            _Float16 xh = (_Float16)v;
            A1[0][r * PADH + hcol] = xh;
            A1[0][16 * PADH + r * PADH + hcol] = (_Float16)((v - (float)xh) * 2048.f);
            float hv = h01 ? h01[(size_t)(row0 + r) * 64 + hcol] : 0.f;
            _Float16 hh = (_Float16)hv;
            A1[0][r * PADH + 64 + hcol] = hh;
            A1[0][16 * PADH + r * PADH + 64 + hcol] = (_Float16)((hv - (float)hh) * 2048.f);
            c[q] = c01 ? c01[(size_t)(row0 + r) * 64 + hcol] : 0.f;
        }
    } else {
        #pragma unroll
        for (int q = 0; q < 4; ++q) {
            const int r = 4 * lkg + q;
            float hv = h02 ? h02[(size_t)(row0 + r) * 64 + hcol] : 0.f;
            _Float16 hh = (_Float16)hv;
            A2[0][r * PADH + 64 + hcol] = hh;
            A2[0][16 * PADH + r * PADH + 64 + hcol] = (_Float16)((hv - (float)hh) * 2048.f);
            c[q] = c02 ? c02[(size_t)(row0 + r) * 64 + hcol] : 0.f;
        }
    }

    const int aoff = lrow * PADH + lkg * 8;

    for (int i = 0; i <= S; ++i) {
        // one barrier per step: LDS writes drained, global stores left in flight
        asm volatile("s_waitcnt lgkmcnt(0)" ::: "memory");
        __builtin_amdgcn_s_barrier();
        __builtin_amdgcn_sched_barrier(0);

        if (!isL2w) {
            if (i < S) {
                float xn[4];
                if (i + 1 < S) {
                    #pragma unroll
                    for (int q = 0; q < 4; ++q) {
                        const int r = 4 * lkg + q;
                        const float* pn = (mode == 1)
                            ? (inseq + ((size_t)(row0 + r) * S + i) * 64)       // target[i]
                            : (inseq + ((size_t)(row0 + r) * S + (i + 1)) * 64);
                        xn[q] = pn[hcol];
                    }
                }
                const _Float16* As = A1[i & 1];
                f32x4 a0[4], a1[4];
                #pragma unroll
                for (int g = 0; g < 4; ++g) {
                    a0[g] = (f32x4){bsv[g], bsv[g], bsv[g], bsv[g]};
                    a1[g] = (f32x4){0.f, 0.f, 0.f, 0.f};
                }
                #pragma unroll
                for (int kt = 0; kt < 4; ++kt) {
                    half8 ah = *(const half8*)&As[aoff + kt * 32];
                    half8 al = *(const half8*)&As[16 * PADH + aoff + kt * 32];
                    #pragma unroll
                    for (int g = 0; g < 4; ++g) {
                        a0[g] = __builtin_amdgcn_mfma_f32_16x16x32_f16(ah, whi[kt][g], a0[g], 0, 0, 0);
                        a1[g] = __builtin_amdgcn_mfma_f32_16x16x32_f16(ah, wlo[kt][g], a1[g], 0, 0, 0);
                        a1[g] = __builtin_amdgcn_mfma_f32_16x16x32_f16(al, whi[kt][g], a1[g], 0, 0, 0);
                    }
                }
                _Float16* Ad1 = A1[(i + 1) & 1];
                _Float16* Ad2 = A2[i & 1];
                #pragma unroll
                for (int q = 0; q < 4; ++q) {
                    const int r = 4 * lkg + q;
                    float gi = a0[0][q] + a1[0][q] * IC_;
                    float gf = a0[1][q] + a1[1][q] * IC_;
                    float gg = a0[2][q] + a1[2][q] * IC_;
                    float go = a0[3][q] + a1[3][q] * IC_;
                    c[q] = fsig(gf) * c[q] + fsig(gi) * ftanh(gg);
                    float hv = fsig(go) * ftanh(c[q]);
                    hlast[q] = hv;
                    _Float16 hh = (_Float16)hv;
                    _Float16 hl = (_Float16)((hv - (float)hh) * 2048.f);
                    Ad1[r * PADH + 64 + hcol] = hh;
                    Ad1[16 * PADH + r * PADH + 64 + hcol] = hl;
                    Ad2[r * PADH + hcol] = hh;
                    Ad2[16 * PADH + r * PADH + hcol] = hl;
                }
                if (i + 1 < S) {
                    #pragma unroll
                    for (int q = 0; q < 4; ++q) {
                        const int r = 4 * lkg + q;
                        _Float16 xh = (_Float16)xn[q];
                        Ad1[r * PADH + hcol] = xh;
                        Ad1[16 * PADH + r * PADH + hcol] =
                            (_Float16)((xn[q] - (float)xh) * 2048.f);
                    }
                }
            }
        } else {
            const int j = i - 1;
            if (j >= 0 && j < S) {
                const _Float16* As = A2[j & 1];
                f32x4 a0[4], a1[4];
                #pragma unroll
                for (int g = 0; g < 4; ++g) {
                    a0[g] = (f32x4){bsv[g], bsv[g], bsv[g], bsv[g]};
                    a1[g] = (f32x4){0.f, 0.f, 0.f, 0.f};
                }
                #pragma unroll
                for (int kt = 0; kt < 4; ++kt) {
                    half8 ah = *(const half8*)&As[aoff + kt * 32];
                    half8 al = *(const half8*)&As[16 * PADH + aoff + kt * 32];
                    #pragma unroll
                    for (int g = 0; g < 4; ++g) {
                        a0[g] = __builtin_amdgcn_mfma_f32_16x16x32_f16(ah, whi[kt][g], a0[g], 0, 0, 0);
                        a1[g] = __builtin_amdgcn_mfma_f32_16x16x32_f16(ah, wlo[kt][g], a1[g], 0, 0, 0);
                        a1[g] = __builtin_amdgcn_mfma_f32_16x16x32_f16(al, whi[kt][g], a1[g], 0, 0, 0);
                    }
                }
                _Float16* Ad = A2[(j + 1) & 1];
                #pragma unroll
                for (int q = 0; q < 4; ++q) {
                    const int r = 4 * lkg + q;
                    float gi = a0[0][q] + a1[0][q] * IC_;
                    float gf = a0[1][q] + a1[1][q] * IC_;
                    float gg = a0[2][q] + a1[2][q] * IC_;
                    float go = a0[3][q] + a1[3][q] * IC_;
                    c[q] = fsig(gf) * c[q] + fsig(gi) * ftanh(gg);
                    float hv = fsig(go) * ftanh(c[q]);
                    hlast[q] = hv;
                    _Float16 hh = (_Float16)hv;
                    Ad[r * PADH + 64 + hcol] = hh;
                    Ad[16 * PADH + r * PADH + 64 + hcol] =
                        (_Float16)((hv - (float)hh) * 2048.f);
                    outseq2[((size_t)(row0 + r) * S + j) * 64 + hcol] = hv;
                }
            }
        }
    }
    if (hf1) {
        float* hdst = isL2w ? hf2 : hf1;
        float* cdst = isL2w ? cf2 : cf1;
        #pragma unroll
        for (int q = 0; q < 4; ++q) {
            const int r = 4 * lkg + q;
            hdst[(size_t)(row0 + r) * 64 + hcol] = hlast[q];
            cdst[(size_t)(row0 + r) * 64 + hcol] = c[q];
        }
    }
}

// ---------------------------------------------------------------------------
// Helper: stage a fp32 row-block into hi/lo fp16 LDS planes [R][72] (attn0)
// ---------------------------------------------------------------------------
__device__ __forceinline__ void stage_split(const float* __restrict__ src,
                                            _Float16* dst, int plane,
                                            int row, int c0) {
    #pragma unroll
    for (int u = 0; u < 4; ++u) {
        float4 v = *(const float4*)(src + u * 4);
        half4 hi, lo;
        hi[0] = (_Float16)v.x; lo[0] = (_Float16)((v.x - (float)hi[0]) * 2048.f);
        hi[1] = (_Float16)v.y; lo[1] = (_Float16)((v.y - (float)hi[1]) * 2048.f);
        hi[2] = (_Float16)v.z; lo[2] = (_Float16)((v.z - (float)hi[2]) * 2048.f);
        hi[3] = (_Float16)v.w; lo[3] = (_Float16)((v.w - (float)hi[3]) * 2048.f);
        *(half4*)&dst[row * 72 + c0 + u * 4] = hi;
        *(half4*)&dst[plane + row * 72 + c0 + u * 4] = lo;
    }
}

// ---------------------------------------------------------------------------
// Self-attention, last query only (round-3 known-good).
// ---------------------------------------------------------------------------
__global__ __launch_bounds__(256) void attn0_mfma(
    const float* __restrict__ encout,
    const _Float16* __restrict__ wqkvh,
    const float* __restrict__ bqkv,
    const float* __restrict__ Wqkv,
    const float* __restrict__ Wo,
    const float* __restrict__ bo,
    float* __restrict__ a0last)
{
    __shared__ __align__(16) _Float16 E16[2 * 4608];
    __shared__ __align__(16) _Float16 K16[2 * 4608];
    __shared__ __align__(16) _Float16 V16[4608];
    __shared__ float qv[64];
    __shared__ float wrow[4 * 68];
    __shared__ float ov[64];

    const int b = blockIdx.x, tid = threadIdx.x;
    const int w = tid >> 6, l = tid & 63, lr = l & 15, lkg = l >> 4;

    {
        int row = tid >> 2, c0 = (tid & 3) * 16;
        stage_split(encout + (size_t)b * 4096 + row * 64 + c0, E16, 4608, row, c0);
    }
    __syncthreads();

    for (int tt = w; tt < 8; tt += 4) {
        const int kind = (tt < 4) ? 0 : 1;
        const int mrow = (kind ? tt - 4 : tt) * 16;
        const int wrowB = kind ? 128 : 64;
        half8 ah[2], al[2];
        #pragma unroll
        for (int kt = 0; kt < 2; ++kt) {
            int ao = (mrow + lr) * 72 + kt * 32 + lkg * 8;
            ah[kt] = *(const half8*)&E16[ao];
            al[kt] = *(const half8*)&E16[4608 + ao];
        }
        #pragma unroll
        for (int nt = 0; nt < 4; ++nt) {
            const int col = nt * 16 + lr;
            const float bv = bqkv[wrowB + col];
            f32x4 a0 = (f32x4){bv, bv, bv, bv};
            f32x4 a1 = (f32x4){0.f, 0.f, 0.f, 0.f};
            #pragma unroll
            for (int kt = 0; kt < 2; ++kt) {
                const _Float16* wp = wqkvh + (size_t)(wrowB + col) * 64 + kt * 32 + lkg * 8;
                half8 bh = *(const half8*)wp;
                half8 bl = *(const half8*)(wp + 12288);
                a0 = __builtin_amdgcn_mfma_f32_16x16x32_f16(ah[kt], bh, a0, 0, 0, 0);
                a1 = __builtin_amdgcn_mfma_f32_16x16x32_f16(ah[kt], bl, a1, 0, 0, 0);
                a1 = __builtin_amdgcn_mfma_f32_16x16x32_f16(al[kt], bh, a1, 0, 0, 0);
            }
            #pragma unroll
            for (int i = 0; i < 4; ++i) {
                float g = a0[i] + a1[i] * IC_;
                int r = mrow + lkg * 4 + i;
                if (kind == 0) {
                    _Float16 gh = (_Float16)g;
                    K16[r * 72 + col] = gh;
                    K16[4608 + r * 72 + col] = (_Float16)((g - (float)gh) * 2048.f);
                } else {
                    V16[r * 72 + col] = (_Float16)g;
                }
            }
        }
    }
    if (w == 3) {
        float a = bqkv[l];
        for (int k = 0; k < 64; ++k) {
            float e = (float)E16[63 * 72 + k] + (float)E16[4608 + 63 * 72 + k] * IC_;
            a += e * Wqkv[l * 64 + k];
        }
        qv[l] = a;
    }
    __syncthreads();

    {
        const int h = tid >> 6, kv = tid & 63;
        float s = 0.f;
        #pragma unroll
        for (int d = 0; d < 16; ++d) {
            float kk = (float)K16[kv * 72 + h * 16 + d]
                     + (float)K16[4608 + kv * 72 + h * 16 + d] * IC_;
            s += qv[h * 16 + d] * kk;
        }
        s *= 0.25f;
        float m = s;
        #pragma unroll
        for (int off = 32; off; off >>= 1) m = fmaxf(m, __shfl_xor(m, off));
        float e = __expf(s - m);
        float sum = e;
        #pragma unroll
        for (int off = 32; off; off >>= 1) sum += __shfl_xor(sum, off);
        wrow[h * 68 + kv] = e / sum;
    }
    __syncthreads();
    if (tid < 64) {
        const int h = tid >> 4, d = tid & 15;
        float o = 0.f;
        for (int kv = 0; kv < 64; ++kv)
            o += wrow[h * 68 + kv] * (float)V16[kv * 72 + h * 16 + d];
        ov[tid] = o;
    }
    __syncthreads();
    if (tid < 64) {
        float a = bo[tid];
        for (int k = 0; k < 64; ++k) a += ov[k] * Wo[tid * 64 + k];
        a0last[(size_t)b * 64 + tid] = a;
    }
}

// ---------------------------------------------------------------------------
// Cross-attention v2 (round-4 known-good): one b per block, S^T scores,
// no atomics, 4 barriers, 40960 B dynamic LDS.
// ---------------------------------------------------------------------------
__global__ __launch_bounds__(256, 4) void cross_attn_v2(
    const float* __restrict__ encout, const float* __restrict__ decout,
    const _Float16* __restrict__ wqkvh, const float* __restrict__ bqkv,
    _Float16* __restrict__ AOg, float* __restrict__ attnw)
{
    extern __shared__ __align__(16) char smem[];
    _Float16* E  = (_Float16*)(smem);
    _Float16* D  = (_Float16*)(smem + 9216);
    _Float16* K  = (_Float16*)(smem + 16128);
    _Float16* Q  = (_Float16*)(smem + 25344);
    _Float16* VT = (_Float16*)(smem + 32256);

    const int b = blockIdx.x, tid = threadIdx.x;
    const int w = tid >> 6, l = tid & 63, lr = l & 15, lkg = l >> 4;
    const int h = w;

    {
        int row = tid >> 2, c0 = (tid & 3) * 16;
        const float* ep = encout + (size_t)b * 4096 + row * 64 + c0;
        half8 v0, v1;
        #pragma unroll
        for (int j = 0; j < 8; ++j) v0[j] = (_Float16)ep[j];
        #pragma unroll
        for (int j = 0; j < 8; ++j) v1[j] = (_Float16)ep[8 + j];
        *(half8*)&E[row * 72 + c0] = v0;
        *(half8*)&E[row * 72 + c0 + 8] = v1;
        if (row < 48) {
            const float* dp = decout + (size_t)b * 3072 + row * 64 + c0;
            half8 u0, u1;
            #pragma unroll
            for (int j = 0; j < 8; ++j) u0[j] = (_Float16)dp[j];
            #pragma unroll
            for (int j = 0; j < 8; ++j) u1[j] = (_Float16)dp[8 + j];
            *(half8*)&D[row * 72 + c0] = u0;
            *(half8*)&D[row * 72 + c0 + 8] = u1;
        }
    }
    __syncthreads();

    for (int tt = w; tt < 11; tt += 4) {
        const int kind = (tt < 4) ? 0 : ((tt < 8) ? 1 : 2);
        const int mrow = ((kind == 0) ? tt : (kind == 1) ? tt - 4 : tt - 8) * 16;
        const int wrowB = (kind == 0) ? 64 : ((kind == 1) ? 128 : 0);
        const _Float16* S = (kind == 2) ? D : E;
        half8 ah[2];
        #pragma unroll
        for (int kt = 0; kt < 2; ++kt)
            ah[kt] = *(const half8*)&S[(mrow + lr) * 72 + kt * 32 + lkg * 8];
        #pragma unroll
        for (int nt = 0; nt < 4; ++nt) {
            const int col = nt * 16 + lr;
            const float bv = bqkv[wrowB + col];
            f32x4 a0 = (f32x4){bv, bv, bv, bv};
            #pragma unroll
            for (int kt = 0; kt < 2; ++kt) {
                half8 bh = *(const half8*)&wqkvh[(size_t)(wrowB + col) * 64 + kt * 32 + lkg * 8];
                a0 = __builtin_amdgcn_mfma_f32_16x16x32_f16(ah[kt], bh, a0, 0, 0, 0);
            }
            if (kind == 1) {
                half4 p;
                #pragma unroll
                for (int i = 0; i < 4; ++i) p[i] = (_Float16)a0[i];
                *(half4*)&VT[col * 68 + mrow + lkg * 4] = p;
            } else {
                _Float16* dst = (kind == 0) ? K : Q;
                #pragma unroll
                for (int i = 0; i < 4; ++i)
                    dst[(mrow + lkg * 4 + i) * 72 + col] = (_Float16)a0[i];
            }
        }
    }
    __syncthreads();

    const half8 z = {0, 0, 0, 0, 0, 0, 0, 0};
    half8 ka[4], qb[3];
    #pragma unroll
    for (int kvt = 0; kvt < 4; ++kvt)
        ka[kvt] = (lkg < 2) ? *(const half8*)&K[(kvt * 16 + lr) * 72 + h * 16 + lkg * 8] : z;
    #pragma unroll
    for (int qt = 0; qt < 3; ++qt)
        qb[qt] = (lkg < 2) ? *(const half8*)&Q[(qt * 16 + lr) * 72 + h * 16 + lkg * 8] : z;
    __syncthreads();

    _Float16* strip = (_Float16*)(smem + ((h == 0) ? 0 : (h == 1) ? 9216
                                        : (h == 2) ? 16128 : 25344));
    {
        f32x4 s[3][4];
        #pragma unroll
        for (int qt = 0; qt < 3; ++qt) {
            #pragma unroll
            for (int kvt = 0; kvt < 4; ++kvt) {
                f32x4 a0 = (f32x4){0.f, 0.f, 0.f, 0.f};
                a0 = __builtin_amdgcn_mfma_f32_16x16x32_f16(ka[kvt], qb[qt], a0, 0, 0, 0);
                s[qt][kvt] = a0 * 0.25f;
            }
            float m = s[qt][0][0];
            #pragma unroll
            for (int kvt = 0; kvt < 4; ++kvt)
                #pragma unroll
                for (int i = 0; i < 4; ++i) m = fmaxf(m, s[qt][kvt][i]);
            m = fmaxf(m, __shfl_xor(m, 16));
            m = fmaxf(m, __shfl_xor(m, 32));
            float sum = 0.f;
            #pragma unroll
            for (int kvt = 0; kvt < 4; ++kvt)
                #pragma unroll
                for (int i = 0; i < 4; ++i) {
                    float e = __expf(s[qt][kvt][i] - m);
                    s[qt][kvt][i] = e;
                    sum += e;
                }
            sum += __shfl_xor(sum, 16);
            sum += __shfl_xor(sum, 32);
            const float r = 1.0f / sum;
            #pragma unroll
            for (int kvt = 0; kvt < 4; ++kvt) {
                half4 p;
                #pragma unroll
                for (int i = 0; i < 4; ++i) p[i] = (_Float16)(s[qt][kvt][i] * r);
                *(half4*)&strip[(qt * 16 + lr) * 72 + kvt * 16 + lkg * 4] = p;
            }
        }
    }
    {
        half8 vb[2];
        #pragma unroll
        for (int kt = 0; kt < 2; ++kt) {
            half4 lo4 = *(const half4*)&VT[(h * 16 + lr) * 68 + kt * 32 + lkg * 8];
            half4 hi4 = *(const half4*)&VT[(h * 16 + lr) * 68 + kt * 32 + lkg * 8 + 4];
            #pragma unroll
            for (int j = 0; j < 4; ++j) { vb[kt][j] = lo4[j]; vb[kt][4 + j] = hi4[j]; }
        }
        #pragma unroll
        for (int qt = 0; qt < 3; ++qt) {
            f32x4 acc = (f32x4){0.f, 0.f, 0.f, 0.f};
            #pragma unroll
            for (int kt = 0; kt < 2; ++kt) {
                half8 wa = *(const half8*)&strip[(qt * 16 + lr) * 72 + kt * 32 + lkg * 8];
                acc = __builtin_amdgcn_mfma_f32_16x16x32_f16(wa, vb[kt], acc, 0, 0, 0);
            }
            #pragma unroll
            for (int i = 0; i < 4; ++i)
                AOg[((size_t)b * 48 + qt * 16 + lkg * 4 + i) * 64 + h * 16 + lr] =
                    (_Float16)acc[i];
        }
    }
    __syncthreads();

    {
        const _Float16* s0 = (const _Float16*)(smem);
        const _Float16* s1 = (const _Float16*)(smem + 9216);
        const _Float16* s2 = (const _Float16*)(smem + 16128);
        const _Float16* s3 = (const _Float16*)(smem + 25344);
        #pragma unroll
        for (int it = 0; it < 12; ++it) {
            int idx = tid + it * 256;
            int o = (idx >> 6) * 72 + (idx & 63);
            attnw[(size_t)b * 3072 + idx] =
                0.25f * ((float)s0[o] + (float)s1[o] + (float)s2[o] + (float)s3[o]);
        }
    }
}

// ---------------------------------------------------------------------------
// Batched out-proj + FC1(relu) + FC2. 64 rows/block, zero barriers.
// ---------------------------------------------------------------------------
__global__ __launch_bounds__(256) void proj_fc_kernel(
    const _Float16* __restrict__ AOg,
    const _Float16* __restrict__ woh, const float* __restrict__ bo,
    const _Float16* __restrict__ w1h, const float* __restrict__ b1,
    const float* __restrict__ W2,     const float* __restrict__ b2,
    float* __restrict__ pred)
{
    __shared__ __align__(16) _Float16 obuf[4][16 * 72];
    __shared__ float h1buf[4][16 * 36];
    const int tid = threadIdx.x;
    const int w = tid >> 6, l = tid & 63, lr = l & 15, lkg = l >> 4;
    const size_t r0 = (size_t)blockIdx.x * 64 + w * 16;

    half8 ah[2];
    #pragma unroll
    for (int kt = 0; kt < 2; ++kt)
        ah[kt] = *(const half8*)&AOg[(r0 + lr) * 64 + kt * 32 + lkg * 8];
    #pragma unroll
    for (int nt = 0; nt < 4; ++nt) {
        const int col = nt * 16 + lr;
        const float bv = bo[col];
        f32x4 a0 = (f32x4){bv, bv, bv, bv};
        #pragma unroll
        for (int kt = 0; kt < 2; ++kt) {
            half8 bh = *(const half8*)&woh[(size_t)col * 64 + kt * 32 + lkg * 8];
            a0 = __builtin_amdgcn_mfma_f32_16x16x32_f16(ah[kt], bh, a0, 0, 0, 0);
        }
        #pragma unroll
        for (int i = 0; i < 4; ++i)
            obuf[w][(lkg * 4 + i) * 72 + col] = (_Float16)a0[i];
    }
    half8 oh[2];
    #pragma unroll
    for (int kt = 0; kt < 2; ++kt)
        oh[kt] = *(const half8*)&obuf[w][lr * 72 + kt * 32 + lkg * 8];
    #pragma unroll
    for (int nt = 0; nt < 2; ++nt) {
        const int m = nt * 16 + lr;
        const float bv = b1[m];
        f32x4 a0 = (f32x4){bv, bv, bv, bv};
        #pragma unroll
        for (int kt = 0; kt < 2; ++kt) {
            half8 bh = *(const half8*)&w1h[(size_t)m * 64 + kt * 32 + lkg * 8];
            a0 = __builtin_amdgcn_mfma_f32_16x16x32_f16(oh[kt], bh, a0, 0, 0, 0);
        }
        #pragma unroll
        for (int i = 0; i < 4; ++i)
            h1buf[w][(lkg * 4 + i) * 36 + m] = fmaxf(a0[i], 0.f);
    }
    if (l < 48) {
        const int q = l / 3, n = l - 3 * q;
        float a = b2[n];
        #pragma unroll
        for (int m2 = 0; m2 < 32; ++m2)
            a += h1buf[w][q * 36 + m2] * W2[n * 32 + m2];
        pred[(r0 + q) * 3 + n] = a;
    }
}

// ---------------------------------------------------------------------------
extern "C" void kernel_launch(void* const* d_in, const int* in_sizes, int n_in,
                              void* d_out, int out_size, void* d_ws, size_t ws_size,
                              hipStream_t stream) {
    const float* x      = (const float*)d_in[0];
    const float* target = (const float*)d_in[1];
    const float* eWih0 = (const float*)d_in[2],  *eWhh0 = (const float*)d_in[3];
    const float* ebih0 = (const float*)d_in[4],  *ebhh0 = (const float*)d_in[5];
    const float* eWih1 = (const float*)d_in[6],  *eWhh1 = (const float*)d_in[7];
    const float* ebih1 = (const float*)d_in[8],  *ebhh1 = (const float*)d_in[9];
    const float* dWih0 = (const float*)d_in[10], *dWhh0 = (const float*)d_in[11];
    const float* dbih0 = (const float*)d_in[12], *dbhh0 = (const float*)d_in[13];
    const float* dWih1 = (const float*)d_in[14], *dWhh1 = (const float*)d_in[15];
    const float* dbih1 = (const float*)d_in[16], *dbhh1 = (const float*)d_in[17];
    const float* Wqkv = (const float*)d_in[18], *bqkv = (const float*)d_in[19];
    const float* Wo   = (const float*)d_in[20], *bo   = (const float*)d_in[21];
    const float* W1   = (const float*)d_in[22], *b1   = (const float*)d_in[23];
    const float* W2   = (const float*)d_in[24], *b2   = (const float*)d_in[25];

    float* ws = (float*)d_ws;
    float* hseq1  = ws;                                   // AOg alias region
    float* encout = hseq1  + (size_t)B_ * L_ * H_;
    float* decout = encout + (size_t)B_ * L_ * H_;
    float* a0last = decout + (size_t)B_ * T_ * H_;
    float* hfin   = a0last + (size_t)B_ * H_;
    float* cfin   = hfin   + (size_t)2 * B_ * H_;
    float* wtg    = cfin   + (size_t)2 * B_ * H_;
    float* auxw   = wtg    + (size_t)4 * 32768;

    _Float16* wh0 = (_Float16*)(wtg);
    _Float16* wh1 = wh0 + 65536;
    _Float16* wh2 = wh1 + 65536;
    _Float16* wh3 = wh2 + 65536;
    _Float16* wqkvh = (_Float16*)auxw;        // [2][192][64]
    _Float16* woh   = wqkvh + 24576;          // [2][64][64]
    _Float16* w1h   = woh + 8192;             // [2][32][64]
    _Float16* AOg   = (_Float16*)hseq1;

    float* pred  = (float*)d_out;
    float* attnw = pred + (size_t)B_ * T_ * 3;

    transpose_w_kernel<<<64, 256, 0, stream>>>(eWih0, eWhh0, wh0);
    transpose_w_kernel<<<64, 256, 0, stream>>>(eWih1, eWhh1, wh1);
    transpose_w_kernel<<<64, 256, 0, stream>>>(dWih0, dWhh0, wh2);
    transpose_w_kernel<<<64, 256, 0, stream>>>(dWih1, dWhh1, wh3);
    split_aux_kernel<<<72, 256, 0, stream>>>(Wqkv, Wo, W1, wqkvh, woh, w1h);

    // fused encoder (gate-aligned, 1 barrier/step); 256 blocks x 512 thr
    lstm2_mfma_kernel<<<B_ / ROWS, 512, 0, stream>>>(
        x, nullptr, wh0, ebih0, ebhh0, wh1, ebih1, ebhh1,
        nullptr, nullptr, nullptr, nullptr,
        encout, hfin, cfin, hfin + (size_t)B_ * H_, cfin + (size_t)B_ * H_, L_, 0);
    // self-attn, last query
    attn0_mfma<<<B_, 256, 0, stream>>>(encout, wqkvh, bqkv, Wqkv, Wo, bo, a0last);
    // fused decoder
    lstm2_mfma_kernel<<<B_ / ROWS, 512, 0, stream>>>(
        target, a0last, wh2, dbih0, dbhh0, wh3, dbih1, dbhh1,
        hfin, cfin, hfin + (size_t)B_ * H_, cfin + (size_t)B_ * H_,
        decout, nullptr, nullptr, nullptr, nullptr, T_, 1);
    // cross-attention -> AOg, attnw
    cross_attn_v2<<<B_, 256, 40960, stream>>>(
        encout, decout, wqkvh, bqkv, AOg, attnw);
    // out-proj + FC1 + FC2 -> pred
    proj_fc_kernel<<<(B_ * T_) / 64, 256, 0, stream>>>(
        AOg, woh, bo, w1h, b1, W2, b2, pred);
}

// Round 11
// 383.832 us; speedup vs baseline: 1.3010x; 1.0292x over previous
//
#include <hip/hip_runtime.h>
#include <hip/hip_bf16.h>
#include <cstddef>

// ---------------------------------------------------------------------------
// LSTMSeq2Seq: B=4096, L=64, T=48, H=64, NH=4, HD=16, NQ=3
// Round 11: fp16 LSTM output copies feed cross-attn (half staging bytes, no
// cvt); out-proj+FC1+FC2 fused into cross_attn epilogue via operand-swapped
// MFMA (AO/O/H overlay the dead VT region in-place). proj_fc kernel removed.
// ---------------------------------------------------------------------------

#define B_   4096
#define L_   64
#define T_   48
#define H_   64
#define ROWS 16      // batch rows per LSTM block
#define PADH 136     // LSTM A row pad (halves)

using half8  = __attribute__((ext_vector_type(8))) _Float16;
using half4  = __attribute__((ext_vector_type(4))) _Float16;
using f32x4  = __attribute__((ext_vector_type(4))) float;

#define IC_ 4.8828125e-4f   // 2^-11

__device__ __forceinline__ float fsig(float x) {
    return __builtin_amdgcn_rcpf(1.0f + __expf(-x));
}
__device__ __forceinline__ float ftanh(float x) {
    float e = __expf(-2.0f * fabsf(x));
    float r = (1.0f - e) * __builtin_amdgcn_rcpf(1.0f + e);
    return copysignf(r, x);
}

// ---------------------------------------------------------------------------
// LSTM weight split (one-time): whalf[split][gate_row 256][k 128]
// ---------------------------------------------------------------------------
__global__ void transpose_w_kernel(const float* __restrict__ Wih,
                                   const float* __restrict__ Whh,
                                   _Float16* __restrict__ out) {
    int idx = blockIdx.x * 256 + threadIdx.x;
    if (idx >= 16384) return;
    int r = idx >> 6, k = idx & 63;
    float wi = Wih[idx];
    _Float16 hi = (_Float16)wi;
    out[r * 128 + k] = hi;
    out[32768 + r * 128 + k] = (_Float16)((wi - (float)hi) * 2048.0f);
    float wh = Whh[idx];
    hi = (_Float16)wh;
    out[r * 128 + 64 + k] = hi;
    out[32768 + r * 128 + 64 + k] = (_Float16)((wh - (float)hi) * 2048.0f);
}

// Attention weight splits: wqkvh[2][192][64], woh[2][64][64], w1h[2][32][64]
__global__ void split_aux_kernel(const float* __restrict__ Wqkv,
                                 const float* __restrict__ Wo,
                                 const float* __restrict__ W1,
                                 _Float16* __restrict__ wqkvh,
                                 _Float16* __restrict__ woh,
                                 _Float16* __restrict__ w1h) {
    int idx = blockIdx.x * 256 + threadIdx.x;
    if (idx < 12288) {
        float v = Wqkv[idx]; _Float16 h = (_Float16)v;
        wqkvh[idx] = h; wqkvh[12288 + idx] = (_Float16)((v - (float)h) * 2048.f);
    } else if (idx < 16384) {
        int i = idx - 12288;
        float v = Wo[i]; _Float16 h = (_Float16)v;
        woh[i] = h; woh[4096 + i] = (_Float16)((v - (float)h) * 2048.f);
    } else if (idx < 18432) {
        int i = idx - 16384;
        float v = W1[i]; _Float16 h = (_Float16)v;
        w1h[i] = h; w1h[2048 + i] = (_Float16)((v - (float)h) * 2048.f);
    }
}

// ---------------------------------------------------------------------------
// Fused 2-layer LSTM, gate-aligned (round-10 structure). 256 x 512 threads.
// NEW: L2 cell additionally writes an fp16 copy (outh2); fp32 out optional.
// ---------------------------------------------------------------------------
__global__ __launch_bounds__(512, 2) void lstm2_mfma_kernel(
    const float* __restrict__ inseq,
    const float* __restrict__ in0,
    const _Float16* __restrict__ w1half,
    const float* __restrict__ b1ihp, const float* __restrict__ b1hhp,
    const _Float16* __restrict__ w2half,
    const float* __restrict__ b2ihp, const float* __restrict__ b2hhp,
    const float* __restrict__ h01, const float* __restrict__ c01,
    const float* __restrict__ h02, const float* __restrict__ c02,
    float* __restrict__ outseq2,          // nullable fp32 output
    _Float16* __restrict__ outh2,         // fp16 output (always)
    float* __restrict__ hf1, float* __restrict__ cf1,
    float* __restrict__ hf2, float* __restrict__ cf2,
    int S, int mode)
{
    __shared__ __align__(16) _Float16 A1[2][2 * 16 * PADH];
    __shared__ __align__(16) _Float16 A2[2][2 * 16 * PADH];

    const int tid  = threadIdx.x;
    const int w    = tid >> 6;
    const int lrow = tid & 15;
    const int lkg  = (tid >> 4) & 3;
    const int row0 = blockIdx.x * ROWS;

    const bool isL2w = (w >= 4);
    const int  wl    = w & 3;
    const int  hcol  = wl * 16 + lrow;

    const _Float16* wsrc = isL2w ? w2half : w1half;
    const float* bihp = isL2w ? b2ihp : b1ihp;
    const float* bhhp = isL2w ? b2hhp : b1hhp;

    half8 whi[4][4], wlo[4][4];
    #pragma unroll
    for (int kt = 0; kt < 4; ++kt)
        #pragma unroll
        for (int g = 0; g < 4; ++g) {
            const int col = g * 64 + hcol;
            const size_t off = (size_t)col * 128 + kt * 32 + lkg * 8;
            whi[kt][g] = *(const half8*)&wsrc[off];
            wlo[kt][g] = *(const half8*)&wsrc[32768 + off];
        }
    float bsv[4];
    #pragma unroll
    for (int g = 0; g < 4; ++g)
        bsv[g] = bihp[g * 64 + hcol] + bhhp[g * 64 + hcol];

    float c[4], hlast[4] = {0.f, 0.f, 0.f, 0.f};

    if (!isL2w) {
        #pragma unroll
        for (int q = 0; q < 4; ++q) {
            const int r = 4 * lkg + q;
            const float* p0 = (mode == 1) ? (in0 + (size_t)(row0 + r) * 64)
                                          : (inseq + (size_t)(row0 + r) * S * 64);
            float v = p0[hcol];
            _Float16 xh = (_Float16)v;
            A1[0][r * PADH + hcol] = xh;
            A1[0][16 * PADH + r * PADH + hcol] = (_Float16)((v - (float)xh) * 2048.f);
            float hv = h01 ? h01[(size_t)(row0 + r) * 64 + hcol] : 0.f;
            _Float16 hh = (_Float16)hv;
            A1[0][r * PADH + 64 + hcol] = hh;
            A1[0][16 * PADH + r * PADH + 64 + hcol] = (_Float16)((hv - (float)hh) * 2048.f);
            c[q] = c01 ? c01[(size_t)(row0 + r) * 64 + hcol] : 0.f;
        }
    } else {
        #pragma unroll
        for (int q = 0; q < 4; ++q) {
            const int r = 4 * lkg + q;
            float hv = h02 ? h02[(size_t)(row0 + r) * 64 + hcol] : 0.f;
            _Float16 hh = (_Float16)hv;
            A2[0][r * PADH + 64 + hcol] = hh;
            A2[0][16 * PADH + r * PADH + 64 + hcol] = (_Float16)((hv - (float)hh) * 2048.f);
            c[q] = c02 ? c02[(size_t)(row0 + r) * 64 + hcol] : 0.f;
        }
    }

    const int aoff = lrow * PADH + lkg * 8;

    for (int i = 0; i <= S; ++i) {
        asm volatile("s_waitcnt lgkmcnt(0)" ::: "memory");
        __builtin_amdgcn_s_barrier();
        __builtin_amdgcn_sched_barrier(0);

        if (!isL2w) {
            if (i < S) {
                float xn[4];
                if (i + 1 < S) {
                    #pragma unroll
                    for (int q = 0; q < 4; ++q) {
                        const int r = 4 * lkg + q;
                        const float* pn = (mode == 1)
                            ? (inseq + ((size_t)(row0 + r) * S + i) * 64)
                            : (inseq + ((size_t)(row0 + r) * S + (i + 1)) * 64);
                        xn[q] = pn[hcol];
                    }
                }
                const _Float16* As = A1[i & 1];
                f32x4 a0[4], a1[4];
                #pragma unroll
                for (int g = 0; g < 4; ++g) {
                    a0[g] = (f32x4){bsv[g], bsv[g], bsv[g], bsv[g]};
                    a1[g] = (f32x4){0.f, 0.f, 0.f, 0.f};
                }
                #pragma unroll
                for (int kt = 0; kt < 4; ++kt) {
                    half8 ah = *(const half8*)&As[aoff + kt * 32];
                    half8 al = *(const half8*)&As[16 * PADH + aoff + kt * 32];
                    #pragma unroll
                    for (int g = 0; g < 4; ++g) {
                        a0[g] = __builtin_amdgcn_mfma_f32_16x16x32_f16(ah, whi[kt][g], a0[g], 0, 0, 0);
                        a1[g] = __builtin_amdgcn_mfma_f32_16x16x32_f16(ah, wlo[kt][g], a1[g], 0, 0, 0);
                        a1[g] = __builtin_amdgcn_mfma_f32_16x16x32_f16(al, whi[kt][g], a1[g], 0, 0, 0);
                    }
                }
                _Float16* Ad1 = A1[(i + 1) & 1];
                _Float16* Ad2 = A2[i & 1];
                #pragma unroll
                for (int q = 0; q < 4; ++q) {
                    const int r = 4 * lkg + q;
                    float gi = a0[0][q] + a1[0][q] * IC_;
                    float gf = a0[1][q] + a1[1][q] * IC_;
                    float gg = a0[2][q] + a1[2][q] * IC_;
                    float go = a0[3][q] + a1[3][q] * IC_;
                    c[q] = fsig(gf) * c[q] + fsig(gi) * ftanh(gg);
                    float hv = fsig(go) * ftanh(c[q]);
                    hlast[q] = hv;
                    _Float16 hh = (_Float16)hv;
                    _Float16 hl = (_Float16)((hv - (float)hh) * 2048.f);
                    Ad1[r * PADH + 64 + hcol] = hh;
                    Ad1[16 * PADH + r * PADH + 64 + hcol] = hl;
                    Ad2[r * PADH + hcol] = hh;
                    Ad2[16 * PADH + r * PADH + hcol] = hl;
                }
                if (i + 1 < S) {
                    #pragma unroll
                    for (int q = 0; q < 4; ++q) {
                        const int r = 4 * lkg + q;
                        _Float16 xh = (_Float16)xn[q];
                        Ad1[r * PADH + hcol] = xh;
                        Ad1[16 * PADH + r * PADH + hcol] =
                            (_Float16)((xn[q] - (float)xh) * 2048.f);
                    }
                }
            }
        } else {
            const int j = i - 1;
            if (j >= 0 && j < S) {
                const _Float16* As = A2[j & 1];
                f32x4 a0[4], a1[4];
                #pragma unroll
                for (int g = 0; g < 4; ++g) {
                    a0[g] = (f32x4){bsv[g], bsv[g], bsv[g], bsv[g]};
                    a1[g] = (f32x4){0.f, 0.f, 0.f, 0.f};
                }
                #pragma unroll
                for (int kt = 0; kt < 4; ++kt) {
                    half8 ah = *(const half8*)&As[aoff + kt * 32];
                    half8 al = *(const half8*)&As[16 * PADH + aoff + kt * 32];
                    #pragma unroll
                    for (int g = 0; g < 4; ++g) {
                        a0[g] = __builtin_amdgcn_mfma_f32_16x16x32_f16(ah, whi[kt][g], a0[g], 0, 0, 0);
                        a1[g] = __builtin_amdgcn_mfma_f32_16x16x32_f16(ah, wlo[kt][g], a1[g], 0, 0, 0);
                        a1[g] = __builtin_amdgcn_mfma_f32_16x16x32_f16(al, whi[kt][g], a1[g], 0, 0, 0);
                    }
                }
                _Float16* Ad = A2[(j + 1) & 1];
                #pragma unroll
                for (int q = 0; q < 4; ++q) {
                    const int r = 4 * lkg + q;
                    float gi = a0[0][q] + a1[0][q] * IC_;
                    float gf = a0[1][q] + a1[1][q] * IC_;
                    float gg = a0[2][q] + a1[2][q] * IC_;
                    float go = a0[3][q] + a1[3][q] * IC_;
                    c[q] = fsig(gf) * c[q] + fsig(gi) * ftanh(gg);
                    float hv = fsig(go) * ftanh(c[q]);
                    hlast[q] = hv;
                    _Float16 hh = (_Float16)hv;
                    Ad[r * PADH + 64 + hcol] = hh;
                    Ad[16 * PADH + r * PADH + 64 + hcol] =
                        (_Float16)((hv - (float)hh) * 2048.f);
                    const size_t oidx = ((size_t)(row0 + r) * S + j) * 64 + hcol;
                    if (outseq2) outseq2[oidx] = hv;
                    outh2[oidx] = hh;
                }
            }
        }
    }
    if (hf1) {
        float* hdst = isL2w ? hf2 : hf1;
        float* cdst = isL2w ? cf2 : cf1;
        #pragma unroll
        for (int q = 0; q < 4; ++q) {
            const int r = 4 * lkg + q;
            hdst[(size_t)(row0 + r) * 64 + hcol] = hlast[q];
            cdst[(size_t)(row0 + r) * 64 + hcol] = c[q];
        }
    }
}

// ---------------------------------------------------------------------------
// Helper: stage fp32 row-block into hi/lo fp16 LDS planes [R][72] (attn0)
// ---------------------------------------------------------------------------
__device__ __forceinline__ void stage_split(const float* __restrict__ src,
                                            _Float16* dst, int plane,
                                            int row, int c0) {
    #pragma unroll
    for (int u = 0; u < 4; ++u) {
        float4 v = *(const float4*)(src + u * 4);
        half4 hi, lo;
        hi[0] = (_Float16)v.x; lo[0] = (_Float16)((v.x - (float)hi[0]) * 2048.f);
        hi[1] = (_Float16)v.y; lo[1] = (_Float16)((v.y - (float)hi[1]) * 2048.f);
        hi[2] = (_Float16)v.z; lo[2] = (_Float16)((v.z - (float)hi[2]) * 2048.f);
        hi[3] = (_Float16)v.w; lo[3] = (_Float16)((v.w - (float)hi[3]) * 2048.f);
        *(half4*)&dst[row * 72 + c0 + u * 4] = hi;
        *(half4*)&dst[plane + row * 72 + c0 + u * 4] = lo;
    }
}

// ---------------------------------------------------------------------------
// Self-attention, last query only (round-3 known-good; fp32 encout input).
// ---------------------------------------------------------------------------
__global__ __launch_bounds__(256) void attn0_mfma(
    const float* __restrict__ encout,
    const _Float16* __restrict__ wqkvh,
    const float* __restrict__ bqkv,
    const float* __restrict__ Wqkv,
    const float* __restrict__ Wo,
    const float* __restrict__ bo,
    float* __restrict__ a0last)
{
    __shared__ __align__(16) _Float16 E16[2 * 4608];
    __shared__ __align__(16) _Float16 K16[2 * 4608];
    __shared__ __align__(16) _Float16 V16[4608];
    __shared__ float qv[64];
    __shared__ float wrow[4 * 68];
    __shared__ float ov[64];

    const int b = blockIdx.x, tid = threadIdx.x;
    const int w = tid >> 6, l = tid & 63, lr = l & 15, lkg = l >> 4;

    {
        int row = tid >> 2, c0 = (tid & 3) * 16;
        stage_split(encout + (size_t)b * 4096 + row * 64 + c0, E16, 4608, row, c0);
    }
    __syncthreads();

    for (int tt = w; tt < 8; tt += 4) {
        const int kind = (tt < 4) ? 0 : 1;
        const int mrow = (kind ? tt - 4 : tt) * 16;
        const int wrowB = kind ? 128 : 64;
        half8 ah[2], al[2];
        #pragma unroll
        for (int kt = 0; kt < 2; ++kt) {
            int ao = (mrow + lr) * 72 + kt * 32 + lkg * 8;
            ah[kt] = *(const half8*)&E16[ao];
            al[kt] = *(const half8*)&E16[4608 + ao];
        }
        #pragma unroll
        for (int nt = 0; nt < 4; ++nt) {
            const int col = nt * 16 + lr;
            const float bv = bqkv[wrowB + col];
            f32x4 a0 = (f32x4){bv, bv, bv, bv};
            f32x4 a1 = (f32x4){0.f, 0.f, 0.f, 0.f};
            #pragma unroll
            for (int kt = 0; kt < 2; ++kt) {
                const _Float16* wp = wqkvh + (size_t)(wrowB + col) * 64 + kt * 32 + lkg * 8;
                half8 bh = *(const half8*)wp;
                half8 bl = *(const half8*)(wp + 12288);
                a0 = __builtin_amdgcn_mfma_f32_16x16x32_f16(ah[kt], bh, a0, 0, 0, 0);
                a1 = __builtin_amdgcn_mfma_f32_16x16x32_f16(ah[kt], bl, a1, 0, 0, 0);
                a1 = __builtin_amdgcn_mfma_f32_16x16x32_f16(al[kt], bh, a1, 0, 0, 0);
            }
            #pragma unroll
            for (int i = 0; i < 4; ++i) {
                float g = a0[i] + a1[i] * IC_;
                int r = mrow + lkg * 4 + i;
                if (kind == 0) {
                    _Float16 gh = (_Float16)g;
                    K16[r * 72 + col] = gh;
                    K16[4608 + r * 72 + col] = (_Float16)((g - (float)gh) * 2048.f);
                } else {
                    V16[r * 72 + col] = (_Float16)g;
                }
            }
        }
    }
    if (w == 3) {
        float a = bqkv[l];
        for (int k = 0; k < 64; ++k) {
            float e = (float)E16[63 * 72 + k] + (float)E16[4608 + 63 * 72 + k] * IC_;
            a += e * Wqkv[l * 64 + k];
        }
        qv[l] = a;
    }
    __syncthreads();

    {
        const int h = tid >> 6, kv = tid & 63;
        float s = 0.f;
        #pragma unroll
        for (int d = 0; d < 16; ++d) {
            float kk = (float)K16[kv * 72 + h * 16 + d]
                     + (float)K16[4608 + kv * 72 + h * 16 + d] * IC_;
            s += qv[h * 16 + d] * kk;
        }
        s *= 0.25f;
        float m = s;
        #pragma unroll
        for (int off = 32; off; off >>= 1) m = fmaxf(m, __shfl_xor(m, off));
        float e = __expf(s - m);
        float sum = e;
        #pragma unroll
        for (int off = 32; off; off >>= 1) sum += __shfl_xor(sum, off);
        wrow[h * 68 + kv] = e / sum;
    }
    __syncthreads();
    if (tid < 64) {
        const int h = tid >> 4, d = tid & 15;
        float o = 0.f;
        for (int kv = 0; kv < 64; ++kv)
            o += wrow[h * 68 + kv] * (float)V16[kv * 72 + h * 16 + d];
        ov[tid] = o;
    }
    __syncthreads();
    if (tid < 64) {
        float a = bo[tid];
        for (int k = 0; k < 64; ++k) a += ov[k] * Wo[tid * 64 + k];
        a0last[(size_t)b * 64 + tid] = a;
    }
}

// ---------------------------------------------------------------------------
// Cross-attention v3: fp16 staging, fused out-proj+FC1+FC2 epilogue.
// One b per block, 5 barriers, 40960 B dynamic LDS, 4 blocks/CU.
// Regions: E[64][72]@0, D[48][72]@9216, K[64][72]@16128, Q[48][72]@25344,
//          VT[64][68]@32256. Strips (w per head) alias E/D/K/Q after b3.
//          AO[48][72] fp16 aliases VT after b4; O then H(f32,stride36)
//          overlay AO in-place per-wave row band (same-wave LDS ordering).
// ---------------------------------------------------------------------------
__global__ __launch_bounds__(256, 4) void cross_attn_v3(
    const _Float16* __restrict__ ench, const _Float16* __restrict__ dech,
    const _Float16* __restrict__ wqkvh, const float* __restrict__ bqkv,
    const _Float16* __restrict__ woh,   const float* __restrict__ bo,
    const _Float16* __restrict__ w1h,   const float* __restrict__ b1,
    const float* __restrict__ W2,       const float* __restrict__ b2,
    float* __restrict__ pred, float* __restrict__ attnw)
{
    extern __shared__ __align__(16) char smem[];
    _Float16* E  = (_Float16*)(smem);
    _Float16* D  = (_Float16*)(smem + 9216);
    _Float16* K  = (_Float16*)(smem + 16128);
    _Float16* Q  = (_Float16*)(smem + 25344);
    _Float16* VT = (_Float16*)(smem + 32256);
    _Float16* AO = (_Float16*)(smem + 32256);   // [48][72] after b4
    float*    Hl = (float*)(smem + 32256);      // [48][36] overlays AO rows

    const int b = blockIdx.x, tid = threadIdx.x;
    const int w = tid >> 6, l = tid & 63, lr = l & 15, lkg = l >> 4;
    const int h = w;

    // ---- P0: stage E, D directly from fp16 ---------------------------------
    {
        int row = tid >> 2, c0 = (tid & 3) * 16;
        const _Float16* ep = ench + (size_t)b * 4096 + row * 64 + c0;
        *(half8*)&E[row * 72 + c0]     = *(const half8*)ep;
        *(half8*)&E[row * 72 + c0 + 8] = *(const half8*)(ep + 8);
        if (row < 48) {
            const _Float16* dp = dech + (size_t)b * 3072 + row * 64 + c0;
            *(half8*)&D[row * 72 + c0]     = *(const half8*)dp;
            *(half8*)&D[row * 72 + c0 + 8] = *(const half8*)(dp + 8);
        }
    }
    __syncthreads();   // b1

    // ---- P1: K/V/Q projections ---------------------------------------------
    for (int tt = w; tt < 11; tt += 4) {
        const int kind = (tt < 4) ? 0 : ((tt < 8) ? 1 : 2);
        const int mrow = ((kind == 0) ? tt : (kind == 1) ? tt - 4 : tt - 8) * 16;
        const int wrowB = (kind == 0) ? 64 : ((kind == 1) ? 128 : 0);
        const _Float16* S = (kind == 2) ? D : E;
        half8 ah[2];
        #pragma unroll
        for (int kt = 0; kt < 2; ++kt)
            ah[kt] = *(const half8*)&S[(mrow + lr) * 72 + kt * 32 + lkg * 8];
        #pragma unroll
        for (int nt = 0; nt < 4; ++nt) {
            const int col = nt * 16 + lr;
            const float bv = bqkv[wrowB + col];
            f32x4 a0 = (f32x4){bv, bv, bv, bv};
            #pragma unroll
            for (int kt = 0; kt < 2; ++kt) {
                half8 bh = *(const half8*)&wqkvh[(size_t)(wrowB + col) * 64 + kt * 32 + lkg * 8];
                a0 = __builtin_amdgcn_mfma_f32_16x16x32_f16(ah[kt], bh, a0, 0, 0, 0);
            }
            if (kind == 1) {
                half4 p;
                #pragma unroll
                for (int i = 0; i < 4; ++i) p[i] = (_Float16)a0[i];
                *(half4*)&VT[col * 68 + mrow + lkg * 4] = p;
            } else {
                _Float16* dst = (kind == 0) ? K : Q;
                #pragma unroll
                for (int i = 0; i < 4; ++i)
                    dst[(mrow + lkg * 4 + i) * 72 + col] = (_Float16)a0[i];
            }
        }
    }
    __syncthreads();   // b2

    // ---- P2a: load score fragments -----------------------------------------
    const half8 z = {0, 0, 0, 0, 0, 0, 0, 0};
    half8 ka[4], qb[3];
    #pragma unroll
    for (int kvt = 0; kvt < 4; ++kvt)
        ka[kvt] = (lkg < 2) ? *(const half8*)&K[(kvt * 16 + lr) * 72 + h * 16 + lkg * 8] : z;
    #pragma unroll
    for (int qt = 0; qt < 3; ++qt)
        qb[qt] = (lkg < 2) ? *(const half8*)&Q[(qt * 16 + lr) * 72 + h * 16 + lkg * 8] : z;
    __syncthreads();   // b3: K/Q/E/D dead -> strips may overwrite

    // ---- P2b: S^T scores + softmax -> strips -------------------------------
    _Float16* strip = (_Float16*)(smem + ((h == 0) ? 0 : (h == 1) ? 9216
                                        : (h == 2) ? 16128 : 25344));
    {
        f32x4 s[3][4];
        #pragma unroll
        for (int qt = 0; qt < 3; ++qt) {
            #pragma unroll
            for (int kvt = 0; kvt < 4; ++kvt) {
                f32x4 a0 = (f32x4){0.f, 0.f, 0.f, 0.f};
                a0 = __builtin_amdgcn_mfma_f32_16x16x32_f16(ka[kvt], qb[qt], a0, 0, 0, 0);
                s[qt][kvt] = a0 * 0.25f;
            }
            float m = s[qt][0][0];
            #pragma unroll
            for (int kvt = 0; kvt < 4; ++kvt)
                #pragma unroll
                for (int i = 0; i < 4; ++i) m = fmaxf(m, s[qt][kvt][i]);
            m = fmaxf(m, __shfl_xor(m, 16));
            m = fmaxf(m, __shfl_xor(m, 32));
            float sum = 0.f;
            #pragma unroll
            for (int kvt = 0; kvt < 4; ++kvt)
                #pragma unroll
                for (int i = 0; i < 4; ++i) {
                    float e = __expf(s[qt][kvt][i] - m);
                    s[qt][kvt][i] = e;
                    sum += e;
                }
            sum += __shfl_xor(sum, 16);
            sum += __shfl_xor(sum, 32);
            const float r = 1.0f / sum;
            #pragma unroll
            for (int kvt = 0; kvt < 4; ++kvt) {
                half4 p;
                #pragma unroll
                for (int i = 0; i < 4; ++i) p[i] = (_Float16)(s[qt][kvt][i] * r);
                *(half4*)&strip[(qt * 16 + lr) * 72 + kvt * 16 + lkg * 4] = p;
            }
        }
    }
    // ---- P2c: PV into registers -------------------------------------------
    f32x4 pv[3];
    {
        half8 vb[2];
        #pragma unroll
        for (int kt = 0; kt < 2; ++kt) {
            half4 lo4 = *(const half4*)&VT[(h * 16 + lr) * 68 + kt * 32 + lkg * 8];
            half4 hi4 = *(const half4*)&VT[(h * 16 + lr) * 68 + kt * 32 + lkg * 8 + 4];
            #pragma unroll
            for (int j = 0; j < 4; ++j) { vb[kt][j] = lo4[j]; vb[kt][4 + j] = hi4[j]; }
        }
        #pragma unroll
        for (int qt = 0; qt < 3; ++qt) {
            f32x4 acc = (f32x4){0.f, 0.f, 0.f, 0.f};
            #pragma unroll
            for (int kt = 0; kt < 2; ++kt) {
                half8 wa = *(const half8*)&strip[(qt * 16 + lr) * 72 + kt * 32 + lkg * 8];
                acc = __builtin_amdgcn_mfma_f32_16x16x32_f16(wa, vb[kt], acc, 0, 0, 0);
            }
            pv[qt] = acc;
        }
    }
    __syncthreads();   // b4: all VT reads + strip writes complete

    // ---- P3: AO -> LDS (VT region, row-major [48][72]) ---------------------
    #pragma unroll
    for (int qt = 0; qt < 3; ++qt)
        #pragma unroll
        for (int i = 0; i < 4; ++i)
            AO[(qt * 16 + lkg * 4 + i) * 72 + h * 16 + lr] = (_Float16)pv[qt][i];
    __syncthreads();   // b5: AO complete; strips still intact

    if (w < 3) {
        // ---- out-proj (swapped): A = Wo rows, B = AO rows (wave's band) ----
        half8 bAO[2];
        #pragma unroll
        for (int kt = 0; kt < 2; ++kt)
            bAO[kt] = *(const half8*)&AO[(w * 16 + lr) * 72 + kt * 32 + lkg * 8];
        f32x4 ov[4];
        #pragma unroll
        for (int nt = 0; nt < 4; ++nt) {
            f32x4 acc = *(const f32x4*)&bo[nt * 16 + lkg * 4];
            #pragma unroll
            for (int kt = 0; kt < 2; ++kt) {
                half8 aW = *(const half8*)&woh[(size_t)(nt * 16 + lr) * 64 + kt * 32 + lkg * 8];
                acc = __builtin_amdgcn_mfma_f32_16x16x32_f16(aW, bAO[kt], acc, 0, 0, 0);
            }
            ov[nt] = acc;   // O[n = nt*16+4lkg+i][r = w*16+lr]
        }
        // write O row-major in place over AO (own row band)
        #pragma unroll
        for (int nt = 0; nt < 4; ++nt) {
            half4 p;
            #pragma unroll
            for (int i = 0; i < 4; ++i) p[i] = (_Float16)ov[nt][i];
            *(half4*)&AO[(w * 16 + lr) * 72 + nt * 16 + lkg * 4] = p;
        }
        // ---- FC1 (swapped): A = W1 rows, B = O rows ------------------------
        half8 bO[2];
        #pragma unroll
        for (int kt = 0; kt < 2; ++kt)
            bO[kt] = *(const half8*)&AO[(w * 16 + lr) * 72 + kt * 32 + lkg * 8];
        #pragma unroll
        for (int nt = 0; nt < 2; ++nt) {
            f32x4 acc = *(const f32x4*)&b1[nt * 16 + lkg * 4];
            #pragma unroll
            for (int kt = 0; kt < 2; ++kt) {
                half8 aW = *(const half8*)&w1h[(size_t)(nt * 16 + lr) * 64 + kt * 32 + lkg * 8];
                acc = __builtin_amdgcn_mfma_f32_16x16x32_f16(aW, bO[kt], acc, 0, 0, 0);
            }
            f32x4 rl;
            #pragma unroll
            for (int i = 0; i < 4; ++i) rl[i] = fmaxf(acc[i], 0.f);
            *(f32x4*)&Hl[(w * 16 + lr) * 36 + nt * 16 + lkg * 4] = rl;  // in place
        }
        // ---- FC2 -----------------------------------------------------------
        if (l < 48) {
            const int qr = l / 3, n = l - 3 * qr;
            const int q = w * 16 + qr;
            float a = b2[n];
            #pragma unroll
            for (int m2 = 0; m2 < 32; ++m2) a += Hl[q * 36 + m2] * W2[n * 32 + m2];
            pred[((size_t)b * 48 + q) * 3 + n] = a;
        }
    } else {
        // ---- attnw = head-mean of strips (wave 3) --------------------------
        const _Float16* s0 = (const _Float16*)(smem);
        const _Float16* s1 = (const _Float16*)(smem + 9216);
        const _Float16* s2 = (const _Float16*)(smem + 16128);
        const _Float16* s3 = (const _Float16*)(smem + 25344);
        #pragma unroll 4
        for (int it = 0; it < 48; ++it) {
            int idx = l + it * 64;
            int o = (idx >> 6) * 72 + (idx & 63);
            attnw[(size_t)b * 3072 + idx] =
                0.25f * ((float)s0[o] + (float)s1[o] + (float)s2[o] + (float)s3[o]);
        }
    }
}

// ---------------------------------------------------------------------------
extern "C" void kernel_launch(void* const* d_in, const int* in_sizes, int n_in,
                              void* d_out, int out_size, void* d_ws, size_t ws_size,
                              hipStream_t stream) {
    const float* x      = (const float*)d_in[0];
    const float* target = (const float*)d_in[1];
    const float* eWih0 = (const float*)d_in[2],  *eWhh0 = (const float*)d_in[3];
    const float* ebih0 = (const float*)d_in[4],  *ebhh0 = (const float*)d_in[5];
    const float* eWih1 = (const float*)d_in[6],  *eWhh1 = (const float*)d_in[7];
    const float* ebih1 = (const float*)d_in[8],  *ebhh1 = (const float*)d_in[9];
    const float* dWih0 = (const float*)d_in[10], *dWhh0 = (const float*)d_in[11];
    const float* dbih0 = (const float*)d_in[12], *dbhh0 = (const float*)d_in[13];
    const float* dWih1 = (const float*)d_in[14], *dWhh1 = (const float*)d_in[15];
    const float* dbih1 = (const float*)d_in[16], *dbhh1 = (const float*)d_in[17];
    const float* Wqkv = (const float*)d_in[18], *bqkv = (const float*)d_in[19];
    const float* Wo   = (const float*)d_in[20], *bo   = (const float*)d_in[21];
    const float* W1   = (const float*)d_in[22], *b1   = (const float*)d_in[23];
    const float* W2   = (const float*)d_in[24], *b2   = (const float*)d_in[25];

    float* ws = (float*)d_ws;
    float* hseq1  = ws;                                   // fp16 out copies live here
    float* encout = hseq1  + (size_t)B_ * L_ * H_;
    float* decout = encout + (size_t)B_ * L_ * H_;        // unused now (kept layout)
    float* a0last = decout + (size_t)B_ * T_ * H_;
    float* hfin   = a0last + (size_t)B_ * H_;
    float* cfin   = hfin   + (size_t)2 * B_ * H_;
    float* wtg    = cfin   + (size_t)2 * B_ * H_;
    float* auxw   = wtg    + (size_t)4 * 32768;

    _Float16* wh0 = (_Float16*)(wtg);
    _Float16* wh1 = wh0 + 65536;
    _Float16* wh2 = wh1 + 65536;
    _Float16* wh3 = wh2 + 65536;
    _Float16* wqkvh = (_Float16*)auxw;        // [2][192][64]
    _Float16* woh   = wqkvh + 24576;          // [2][64][64]
    _Float16* w1h   = woh + 8192;             // [2][32][64]
    _Float16* encouth = (_Float16*)hseq1;               // B*L*64 halves
    _Float16* decouth = encouth + (size_t)B_ * L_ * H_; // B*T*64 halves

    float* pred  = (float*)d_out;
    float* attnw = pred + (size_t)B_ * T_ * 3;

    transpose_w_kernel<<<64, 256, 0, stream>>>(eWih0, eWhh0, wh0);
    transpose_w_kernel<<<64, 256, 0, stream>>>(eWih1, eWhh1, wh1);
    transpose_w_kernel<<<64, 256, 0, stream>>>(dWih0, dWhh0, wh2);
    transpose_w_kernel<<<64, 256, 0, stream>>>(dWih1, dWhh1, wh3);
    split_aux_kernel<<<72, 256, 0, stream>>>(Wqkv, Wo, W1, wqkvh, woh, w1h);

    // fused encoder: fp32 encout (for attn0) + fp16 encouth (for cross)
    lstm2_mfma_kernel<<<B_ / ROWS, 512, 0, stream>>>(
        x, nullptr, wh0, ebih0, ebhh0, wh1, ebih1, ebhh1,
        nullptr, nullptr, nullptr, nullptr,
        encout, encouth, hfin, cfin, hfin + (size_t)B_ * H_, cfin + (size_t)B_ * H_,
        L_, 0);
    // self-attn, last query
    attn0_mfma<<<B_, 256, 0, stream>>>(encout, wqkvh, bqkv, Wqkv, Wo, bo, a0last);
    // fused decoder: fp16 output only
    lstm2_mfma_kernel<<<B_ / ROWS, 512, 0, stream>>>(
        target, a0last, wh2, dbih0, dbhh0, wh3, dbih1, dbhh1,
        hfin, cfin, hfin + (size_t)B_ * H_, cfin + (size_t)B_ * H_,
        nullptr, decouth, nullptr, nullptr, nullptr, nullptr, T_, 1);
    // cross-attention + out-proj + FC (fused epilogue) -> pred, attnw
    cross_attn_v3<<<B_, 256, 40960, stream>>>(
        encouth, decouth, wqkvh, bqkv, woh, bo, w1h, b1, W2, b2, pred, attnw);
}